// Round 1
// baseline (906.377 us; speedup 1.0000x reference)
//
#include <hip/hip_runtime.h>
#include <hip/hip_bf16.h>

// ---------------------------------------------------------------------------
// Problem constants
//   B=32, LQ=1024, LIN=5376 (4096+1024+256), D=256, NH=8, L=3, P=4, DH=32
//   NH_CA=2, dh_ca=128, M(concepts)=10, NCLS=200
// Outputs (f32, concatenated):
//   out       [32*200   = 6400)   at 0
//   attn_u    [32*10    = 320 )   at 6400
//   attn_n    [32*10    = 320 )   at 6720
//   attn_s    [32*1024*10=327680) at 7040
// ---------------------------------------------------------------------------

__device__ __forceinline__ void store_val(float* p, float v) { *p = v; }
__device__ __forceinline__ void store_val(__hip_bfloat16* p, float v) { *p = __float2bfloat16(v); }

// Tiled f32 GEMM: C[M,N] = A[M,K] @ W[K,N] + bias (+ resid). M%64==0, K%16==0,
// N%4==0 required. 64x64 tile, 256 threads, 4x4 register micro-tile.
template <typename OT, bool RESID>
__global__ __launch_bounds__(256) void gemm_tile(
    const float* __restrict__ A, const float* __restrict__ W,
    const float* __restrict__ bias, const float* __restrict__ resid,
    OT* __restrict__ C, int M, int N, int K)
{
  __shared__ float As[16][68];   // [k][m], stride 68 floats = 272B (16B aligned, bank-spread)
  __shared__ float Ws[16][68];   // [k][n]
  const int tid = threadIdx.x;
  const int m0 = blockIdx.x * 64;
  const int n0 = blockIdx.y * 64;
  const int tx = tid & 15, ty = tid >> 4;
  const int a_m = tid >> 2;           // 0..63
  const int a_k = (tid & 3) << 2;     // 0,4,8,12
  const int w_k = tid >> 4;           // 0..15
  const int w_n = (tid & 15) << 2;    // 0..60
  const int ncol = n0 + w_n;
  float acc[4][4] = {};

  for (int k0 = 0; k0 < K; k0 += 16) {
    float4 av = *reinterpret_cast<const float4*>(&A[(size_t)(m0 + a_m) * K + k0 + a_k]);
    As[a_k + 0][a_m] = av.x;
    As[a_k + 1][a_m] = av.y;
    As[a_k + 2][a_m] = av.z;
    As[a_k + 3][a_m] = av.w;
    float4 wv = {0.f, 0.f, 0.f, 0.f};
    if (ncol < N)
      wv = *reinterpret_cast<const float4*>(&W[(size_t)(k0 + w_k) * N + ncol]);
    *reinterpret_cast<float4*>(&Ws[w_k][w_n]) = wv;
    __syncthreads();
#pragma unroll
    for (int k = 0; k < 16; ++k) {
      float4 a4 = *reinterpret_cast<const float4*>(&As[k][ty << 2]);
      float4 w4 = *reinterpret_cast<const float4*>(&Ws[k][tx << 2]);
      float aa[4] = {a4.x, a4.y, a4.z, a4.w};
      float ww[4] = {w4.x, w4.y, w4.z, w4.w};
#pragma unroll
      for (int i = 0; i < 4; ++i)
#pragma unroll
        for (int j = 0; j < 4; ++j)
          acc[i][j] += aa[i] * ww[j];
    }
    __syncthreads();
  }

  const int cn = n0 + (tx << 2);
  if (cn < N) {
    const float b0 = bias[cn], b1 = bias[cn + 1], b2 = bias[cn + 2], b3 = bias[cn + 3];
#pragma unroll
    for (int i = 0; i < 4; ++i) {
      const int row = m0 + (ty << 2) + i;
      const size_t off = (size_t)row * N + cn;
      float v0 = acc[i][0] + b0, v1 = acc[i][1] + b1;
      float v2 = acc[i][2] + b2, v3 = acc[i][3] + b3;
      if constexpr (RESID) {
        v0 += resid[off]; v1 += resid[off + 1]; v2 += resid[off + 2]; v3 += resid[off + 3];
      }
      store_val(&C[off + 0], v0);
      store_val(&C[off + 1], v1);
      store_val(&C[off + 2], v2);
      store_val(&C[off + 3], v3);
    }
  }
}

// kv projections for the three concept sets: dst[10][512] = src[10][256] @ W[256][512] + b
__global__ __launch_bounds__(256) void kv_kernel(
    const float* __restrict__ unsup, const float* __restrict__ conc,
    const float* __restrict__ spat, const float* __restrict__ Wkv_c,
    const float* __restrict__ bkv_c, const float* __restrict__ Wkv_s,
    const float* __restrict__ bkv_s, float* __restrict__ kv_u,
    float* __restrict__ kv_n, float* __restrict__ kv_s)
{
  const int j = blockIdx.x;
  const float* src = (j == 0) ? unsup : ((j == 1) ? conc : spat);
  const float* W   = (j < 2) ? Wkv_c : Wkv_s;
  const float* bb  = (j < 2) ? bkv_c : bkv_s;
  float* dst       = (j == 0) ? kv_u : ((j == 1) ? kv_n : kv_s);
  __shared__ float s[2560];
  for (int i = threadIdx.x; i < 2560; i += 256) s[i] = src[i];
  __syncthreads();
  for (int o = threadIdx.x; o < 5120; o += 256) {
    const int m = o >> 9, n = o & 511;
    float acc = bb[n];
    for (int k = 0; k < 256; ++k) acc += s[m * 256 + k] * W[(size_t)k * 512 + n];
    dst[o] = acc;
  }
}

// Multi-scale deformable attention sampling. One block per (b,q), 256 threads.
// Reads precomputed offsets (192) and attention logits (96), does per-head
// softmax over L*P=12, bilinear-gathers from bf16 value, writes msda_raw.
__global__ __launch_bounds__(256) void msda_kernel(
    const float* __restrict__ off_buf, const float* __restrict__ logit_buf,
    const __hip_bfloat16* __restrict__ value, float* __restrict__ msda_out)
{
  const int bq = blockIdx.x;        // b*1024 + q
  const int q = bq & 1023;
  const int b = bq >> 10;
  const int tid = threadIdx.x;
  __shared__ float lg[96];
  __shared__ float offs[192];
  __shared__ float aw[96];
  __shared__ int sRow[96][4];
  __shared__ float sW[96][4];
  if (tid < 96)  lg[tid]   = logit_buf[(size_t)bq * 96 + tid];
  if (tid < 192) offs[tid] = off_buf[(size_t)bq * 192 + tid];
  __syncthreads();
  if (tid < 8) {   // per-head softmax over 12 logits
    float mx = -1e30f;
#pragma unroll
    for (int i = 0; i < 12; ++i) mx = fmaxf(mx, lg[tid * 12 + i]);
    float e[12];
    float s = 0.f;
#pragma unroll
    for (int i = 0; i < 12; ++i) { e[i] = expf(lg[tid * 12 + i] - mx); s += e[i]; }
    const float inv = 1.f / s;
#pragma unroll
    for (int i = 0; i < 12; ++i) aw[tid * 12 + i] = e[i] * inv;
  }
  __syncthreads();
  if (tid < 96) {  // per (h,l,p): compute 4 corner rows + combined weights
    const int WHl[3] = {64, 32, 16};
    const int St[3] = {0, 4096, 5120};
    const int h = tid / 12, r = tid % 12, l = r >> 2, p_ = r & 3;
    const float ox = offs[h * 24 + l * 8 + p_ * 2 + 0];
    const float oy = offs[h * 24 + l * 8 + p_ * 2 + 1];
    const float refx = ((q & 31) + 0.5f) * (1.0f / 32.0f);
    const float refy = ((q >> 5) + 0.5f) * (1.0f / 32.0f);
    const int WH = WHl[l];
    const float fw = (float)WH;
    const float lx = (refx + ox / fw) * fw - 0.5f;
    const float ly = (refy + oy / fw) * fw - 0.5f;
    const float fx = floorf(lx), fy = floorf(ly);
    const int x0 = (int)fx, y0 = (int)fy;
    const float dx = lx - fx, dy = ly - fy;
    const float a = aw[tid];
#pragma unroll
    for (int c = 0; c < 4; ++c) {
      const int ix = x0 + (c & 1), iy = y0 + (c >> 1);
      const float wb = ((c & 1) ? dx : 1.f - dx) * ((c >> 1) ? dy : 1.f - dy);
      const bool valid = (ix >= 0) && (ix < WH) && (iy >= 0) && (iy < WH);
      const int cx = min(max(ix, 0), WH - 1);
      const int cy = min(max(iy, 0), WH - 1);
      sRow[tid][c] = St[l] + cy * WH + cx;
      sW[tid][c] = valid ? wb * a : 0.f;
    }
  }
  __syncthreads();
  const int h = tid >> 5, d = tid & 31;
  const __hip_bfloat16* vb = value + (size_t)b * (5376 * 256) + h * 32 + d;
  float acc = 0.f;
#pragma unroll
  for (int s = 0; s < 12; ++s) {
    const int cc = h * 12 + s;
#pragma unroll
    for (int c = 0; c < 4; ++c) {
      acc += sW[cc][c] * __bfloat162float(vb[(size_t)sRow[cc][c] * 256]);
    }
  }
  msda_out[(size_t)bq * 256 + tid] = acc;
}

// cls cross-attention (unsup + normal concepts). One 64-thread block per b.
// Computes q = x_cls @ Wq_c + bq_c inline, then both attentions;
// writes attn means to d_out and o_u+o_n (256) to o_un.
__global__ __launch_bounds__(64) void cls_attn_kernel(
    const float* __restrict__ x_cls, const float* __restrict__ Wq_c,
    const float* __restrict__ bq_c, const float* __restrict__ kv_u,
    const float* __restrict__ kv_n, float* __restrict__ o_un,
    float* __restrict__ attn_u_out, float* __restrict__ attn_n_out)
{
  const int b = blockIdx.x;
  const int lane = threadIdx.x;
  __shared__ float xr[256];
  *reinterpret_cast<float4*>(&xr[lane * 4]) =
      *reinterpret_cast<const float4*>(&x_cls[(size_t)b * 256 + lane * 4]);
  __syncthreads();
  float4 q4 = *reinterpret_cast<const float4*>(&bq_c[lane * 4]);
  for (int k = 0; k < 256; ++k) {
    const float xk = xr[k];
    const float4 w = *reinterpret_cast<const float4*>(&Wq_c[(size_t)k * 256 + lane * 4]);
    q4.x += xk * w.x; q4.y += xk * w.y; q4.z += xk * w.z; q4.w += xk * w.w;
  }
  const float scale = 0.08838834764831845f;  // 1/sqrt(128)
  float4 osum = {0.f, 0.f, 0.f, 0.f};
  for (int cs = 0; cs < 2; ++cs) {
    const float* kv = cs ? kv_n : kv_u;
    float* aout = cs ? attn_n_out : attn_u_out;
    float attn[10];
    float mx = -1e30f;
#pragma unroll
    for (int m = 0; m < 10; ++m) {
      const float4 k4 = *reinterpret_cast<const float4*>(&kv[m * 512 + lane * 4]);
      float p = q4.x * k4.x + q4.y * k4.y + q4.z * k4.z + q4.w * k4.w;
      p += __shfl_xor(p, 1);  p += __shfl_xor(p, 2);  p += __shfl_xor(p, 4);
      p += __shfl_xor(p, 8);  p += __shfl_xor(p, 16);
      attn[m] = p * scale;
      mx = fmaxf(mx, attn[m]);
    }
    float s = 0.f;
#pragma unroll
    for (int m = 0; m < 10; ++m) { attn[m] = expf(attn[m] - mx); s += attn[m]; }
    const float inv = 1.f / s;
#pragma unroll
    for (int m = 0; m < 10; ++m) {
      attn[m] *= inv;
      const float am = 0.5f * (attn[m] + __shfl_xor(attn[m], 32));
      if (lane == m) aout[b * 10 + m] = am;   // static register index
      const float4 v4 = *reinterpret_cast<const float4*>(&kv[m * 512 + 256 + lane * 4]);
      osum.x += attn[m] * v4.x; osum.y += attn[m] * v4.y;
      osum.z += attn[m] * v4.z; osum.w += attn[m] * v4.w;
    }
  }
  *reinterpret_cast<float4*>(&o_un[(size_t)b * 256 + lane * 4]) = osum;
}

// spatial cross-attention: one wave per query (4 waves/block).
// Writes attn mean (d_out section) and o_s (B,LQ,256).
__global__ __launch_bounds__(256) void spatial_attn_kernel(
    const float* __restrict__ q_s, const float* __restrict__ kv_s,
    float* __restrict__ o_s, float* __restrict__ attn_out)
{
  const int lane = threadIdx.x & 63;
  const int qg = blockIdx.x * 4 + (threadIdx.x >> 6);  // 0..32767
  const float4 q4 = *reinterpret_cast<const float4*>(&q_s[(size_t)qg * 256 + lane * 4]);
  const float scale = 0.08838834764831845f;
  float attn[10];
  float mx = -1e30f;
#pragma unroll
  for (int m = 0; m < 10; ++m) {
    const float4 k4 = *reinterpret_cast<const float4*>(&kv_s[m * 512 + lane * 4]);
    float p = q4.x * k4.x + q4.y * k4.y + q4.z * k4.z + q4.w * k4.w;
    p += __shfl_xor(p, 1);  p += __shfl_xor(p, 2);  p += __shfl_xor(p, 4);
    p += __shfl_xor(p, 8);  p += __shfl_xor(p, 16);
    attn[m] = p * scale;
    mx = fmaxf(mx, attn[m]);
  }
  float s = 0.f;
#pragma unroll
  for (int m = 0; m < 10; ++m) { attn[m] = expf(attn[m] - mx); s += attn[m]; }
  const float inv = 1.f / s;
  float4 o4 = {0.f, 0.f, 0.f, 0.f};
#pragma unroll
  for (int m = 0; m < 10; ++m) {
    attn[m] *= inv;
    const float am = 0.5f * (attn[m] + __shfl_xor(attn[m], 32));
    if (lane == m) attn_out[(size_t)qg * 10 + m] = am;
    const float4 v4 = *reinterpret_cast<const float4*>(&kv_s[m * 512 + 256 + lane * 4]);
    o4.x += attn[m] * v4.x; o4.y += attn[m] * v4.y;
    o4.z += attn[m] * v4.z; o4.w += attn[m] * v4.w;
  }
  *reinterpret_cast<float4*>(&o_s[(size_t)qg * 256 + lane * 4]) = o4;
}

// partial reduction of o_s over queries: (b, chunk of 64 q) -> o_spart[b][ch][256]
__global__ __launch_bounds__(256) void reduce_os_kernel(
    const float* __restrict__ o_s, float* __restrict__ o_spart)
{
  const int b = blockIdx.x, ch = blockIdx.y, d = threadIdx.x;
  const float* p = o_s + ((size_t)b * 1024 + ch * 64) * 256 + d;
  float s = 0.f;
  for (int i = 0; i < 64; ++i) s += p[(size_t)i * 256];
  o_spart[((size_t)b * 16 + ch) * 256 + d] = s;
}

// final classification head:
// out[b,c] = (o_u+o_n)[b]·Wp_c[:,c] + 2*bp_c[c] + mean_q(o_s[b])·Wp_s[:,c] + bp_s[c]
__global__ __launch_bounds__(256) void final_out_kernel(
    const float* __restrict__ o_un, const float* __restrict__ o_spart,
    const float* __restrict__ Wp_c, const float* __restrict__ bp_c,
    const float* __restrict__ Wp_s, const float* __restrict__ bp_s,
    float* __restrict__ out)
{
  const int b = blockIdx.x, c = threadIdx.x;
  __shared__ float ou[256], os[256];
  float s = 0.f;
  for (int ch = 0; ch < 16; ++ch) s += o_spart[((size_t)b * 16 + ch) * 256 + c];
  ou[c] = o_un[(size_t)b * 256 + c];
  os[c] = s * (1.0f / 1024.0f);
  __syncthreads();
  if (c < 200) {
    float acc = 2.f * bp_c[c] + bp_s[c];
    for (int d = 0; d < 256; ++d)
      acc += ou[d] * Wp_c[d * 200 + c] + os[d] * Wp_s[d * 200 + c];
    out[b * 200 + c] = acc;
  }
}

extern "C" void kernel_launch(void* const* d_in, const int* in_sizes, int n_in,
                              void* d_out, int out_size, void* d_ws, size_t ws_size,
                              hipStream_t stream)
{
  const float* query  = (const float*)d_in[0];
  const float* feats  = (const float*)d_in[1];
  const float* x_cls  = (const float*)d_in[2];
  const float* W_off  = (const float*)d_in[3];
  const float* b_off  = (const float*)d_in[4];
  const float* W_attn = (const float*)d_in[5];
  const float* b_attn = (const float*)d_in[6];
  const float* W_val  = (const float*)d_in[7];
  const float* b_val  = (const float*)d_in[8];
  const float* W_out  = (const float*)d_in[9];
  const float* b_out  = (const float*)d_in[10];
  const float* unsup  = (const float*)d_in[11];
  const float* conc   = (const float*)d_in[12];
  const float* spat   = (const float*)d_in[13];
  const float* Wq_c   = (const float*)d_in[14];
  const float* bq_c   = (const float*)d_in[15];
  const float* Wkv_c  = (const float*)d_in[16];
  const float* bkv_c  = (const float*)d_in[17];
  const float* Wp_c   = (const float*)d_in[18];
  const float* bp_c   = (const float*)d_in[19];
  const float* Wq_s   = (const float*)d_in[20];
  const float* bq_s   = (const float*)d_in[21];
  const float* Wkv_s  = (const float*)d_in[22];
  const float* bkv_s  = (const float*)d_in[23];
  const float* Wp_s   = (const float*)d_in[24];
  const float* bp_s   = (const float*)d_in[25];
  float* out = (float*)d_out;

  const int B = 32, LQ = 1024, LIN = 5376, D = 256;
  const int MQ = B * LQ;    // 32768
  const int MV = B * LIN;   // 172032

  // workspace layout (peak ~190 MB):
  //   [0, 88.1MB)  value (bf16)  -> reused after msda for q_s (33.6MB) + o_s (33.6MB)
  //   then f32: off(25.2MB) | logits(12.6MB) | msda_raw(33.6MB) | x(33.6MB) | smalls
  __hip_bfloat16* value = (__hip_bfloat16*)d_ws;
  const size_t val_bytes = (size_t)MV * D * sizeof(__hip_bfloat16);
  float* fbase     = (float*)((char*)d_ws + val_bytes);
  float* off_buf   = fbase;
  float* logit_buf = off_buf + (size_t)MQ * 192;
  float* msda_raw  = logit_buf + (size_t)MQ * 96;
  float* x         = msda_raw + (size_t)MQ * 256;
  float* kv_u      = x + (size_t)MQ * 256;
  float* kv_n      = kv_u + 5120;
  float* kv_s      = kv_n + 5120;
  float* o_un      = kv_s + 5120;
  float* o_spart   = o_un + B * 256;
  // reuse of the (dead) value region after msda_kernel:
  float* q_s = (float*)d_ws;
  float* o_s = q_s + (size_t)MQ * 256;

  dim3 blk(256);
  // value = feats @ W_val + b_val  (bf16 out)
  gemm_tile<__hip_bfloat16, false><<<dim3(MV / 64, 4), blk, 0, stream>>>(
      feats, W_val, b_val, nullptr, value, MV, 256, 256);
  // off = query @ W_off + b_off
  gemm_tile<float, false><<<dim3(MQ / 64, 3), blk, 0, stream>>>(
      query, W_off, b_off, nullptr, off_buf, MQ, 192, 256);
  // logits = query @ W_attn + b_attn
  gemm_tile<float, false><<<dim3(MQ / 64, 2), blk, 0, stream>>>(
      query, W_attn, b_attn, nullptr, logit_buf, MQ, 96, 256);
  // kv projections (3 tiny GEMMs)
  kv_kernel<<<dim3(3), blk, 0, stream>>>(unsup, conc, spat, Wkv_c, bkv_c,
                                         Wkv_s, bkv_s, kv_u, kv_n, kv_s);
  // deformable sampling
  msda_kernel<<<dim3(MQ), blk, 0, stream>>>(off_buf, logit_buf, value, msda_raw);
  // x = query + msda_raw @ W_out + b_out
  gemm_tile<float, true><<<dim3(MQ / 64, 4), blk, 0, stream>>>(
      msda_raw, W_out, b_out, query, x, MQ, 256, 256);
  // q_s = x @ Wq_s + bq_s   (overwrites dead value region)
  gemm_tile<float, false><<<dim3(MQ / 64, 4), blk, 0, stream>>>(
      x, Wq_s, bq_s, nullptr, q_s, MQ, 256, 256);
  // cls branch (out_u + out_n + their attn means)
  cls_attn_kernel<<<dim3(B), dim3(64), 0, stream>>>(
      x_cls, Wq_c, bq_c, kv_u, kv_n, o_un, out + 6400, out + 6720);
  // spatial attention (attn_s mean + o_s)
  spatial_attn_kernel<<<dim3(MQ / 4), blk, 0, stream>>>(q_s, kv_s, o_s, out + 7040);
  // mean over queries (partial) + final head
  reduce_os_kernel<<<dim3(B, 16), blk, 0, stream>>>(o_s, o_spart);
  final_out_kernel<<<dim3(B), blk, 0, stream>>>(o_un, o_spart, Wp_c, bp_c,
                                                Wp_s, bp_s, out);
}

// Round 2
// 543.739 us; speedup vs baseline: 1.6669x; 1.6669x over previous
//
#include <hip/hip_runtime.h>
#include <hip/hip_bf16.h>

// ---------------------------------------------------------------------------
// Problem constants
//   B=32, LQ=1024, LIN=5376 (4096+1024+256), D=256, NH=8, L=3, P=4, DH=32
//   NH_CA=2, dh_ca=128, M(concepts)=10, NCLS=200
// Outputs (f32, concatenated):
//   out[6400) | attn_u[320) | attn_n[320) | attn_s[327680)
// ---------------------------------------------------------------------------

typedef __attribute__((ext_vector_type(8))) short s16x8;   // 8 bf16 (4 VGPRs)
typedef __attribute__((ext_vector_type(4))) float f32x4;

__device__ __forceinline__ void store_val(float* p, float v) { *p = v; }
__device__ __forceinline__ void store_val(__hip_bfloat16* p, float v) { *p = __float2bfloat16(v); }

__device__ __forceinline__ unsigned short f2bf(float x) {
  unsigned int u = __builtin_bit_cast(unsigned int, x);
  u += 0x7FFFu + ((u >> 16) & 1u);            // RNE
  return (unsigned short)(u >> 16);
}

// ---------------------------------------------------------------------------
// bf16-MFMA GEMM: C[M,N] = A[M,K=256] @ W[K=256,N] + bias (+resid).
// f32 inputs converted to bf16 during staging. BM=128, BN=128, BK=64.
// 256 threads = 4 waves (2x2), wave tile 64x64 = 4x4 frags of 16x16x32.
// LDS: A [row][k] and B^T [col][k], XOR-swizzled (T2) for conflict-free
// ds_read_b128 fragment reads. M%128==0, K==256, N%4 only (masked cols).
// ---------------------------------------------------------------------------
template <typename OT, bool RESID>
__global__ __launch_bounds__(256) void gemm_mfma(
    const float* __restrict__ A, const float* __restrict__ W,
    const float* __restrict__ bias, const float* __restrict__ resid,
    OT* __restrict__ C, int M, int N, int K /* must be 256 */)
{
  __shared__ unsigned short sA[128 * 64];
  __shared__ unsigned short sB[128 * 64];
  char* sAb = (char*)sA;
  char* sBb = (char*)sB;

  const int tid = threadIdx.x;
  const int m0 = blockIdx.x * 128;
  const int n0 = blockIdx.y * 128;
  const int lane = tid & 63;
  const int w = tid >> 6;
  const int wr = (w >> 1) * 64, wc = (w & 1) * 64;
  const int l15 = lane & 15;
  const int lg = lane >> 4;

  // staging assignments
  const int a_row = tid >> 1;           // 0..127
  const int a_ke = (tid & 1) * 32;      // element k base: 0 / 32
  const int b_k8 = (tid >> 5) * 8;      // 0..56
  const int b_c4 = (tid & 31) * 4;      // 0..124
  const bool b_valid = (n0 + b_c4) < N;

  f32x4 acc[4][4] = {};
  f32x4 av[8], bv[8];

  // prologue loads (k0 = 0)
  {
    const float* Ap = &A[(size_t)(m0 + a_row) * 256 + a_ke];
#pragma unroll
    for (int i = 0; i < 8; ++i) av[i] = *reinterpret_cast<const f32x4*>(Ap + i * 4);
#pragma unroll
    for (int i = 0; i < 8; ++i)
      bv[i] = b_valid ? *reinterpret_cast<const f32x4*>(&W[(size_t)(b_k8 + i) * N + n0 + b_c4])
                      : f32x4{0.f, 0.f, 0.f, 0.f};
  }

#pragma unroll
  for (int ks = 0; ks < 4; ++ks) {
    __syncthreads();   // prior fragment reads complete
    // ---- stage A: 4 x 16B swizzled writes ----
#pragma unroll
    for (int c = 0; c < 4; ++c) {
      const f32x4 lo = av[2 * c], hi = av[2 * c + 1];
      uint4 p;
      p.x = (unsigned)f2bf(lo[0]) | ((unsigned)f2bf(lo[1]) << 16);
      p.y = (unsigned)f2bf(lo[2]) | ((unsigned)f2bf(lo[3]) << 16);
      p.z = (unsigned)f2bf(hi[0]) | ((unsigned)f2bf(hi[1]) << 16);
      p.w = (unsigned)f2bf(hi[2]) | ((unsigned)f2bf(hi[3]) << 16);
      const int off = a_row * 128 + ((a_ke * 2 + c * 16) ^ ((a_row & 7) << 4));
      *reinterpret_cast<uint4*>(sAb + off) = p;
    }
    // ---- stage B transposed: col j gets k8..k8+7 ----
#pragma unroll
    for (int j = 0; j < 4; ++j) {
      uint4 p;
      p.x = (unsigned)f2bf(bv[0][j]) | ((unsigned)f2bf(bv[1][j]) << 16);
      p.y = (unsigned)f2bf(bv[2][j]) | ((unsigned)f2bf(bv[3][j]) << 16);
      p.z = (unsigned)f2bf(bv[4][j]) | ((unsigned)f2bf(bv[5][j]) << 16);
      p.w = (unsigned)f2bf(bv[6][j]) | ((unsigned)f2bf(bv[7][j]) << 16);
      const int col = b_c4 + j;
      const int off = col * 128 + ((b_k8 * 2) ^ ((col & 7) << 4));
      *reinterpret_cast<uint4*>(sBb + off) = p;
    }
    __syncthreads();
    // ---- issue next-tile global loads before MFMA (latency overlap) ----
    if (ks < 3) {
      const int k0 = (ks + 1) * 64;
      const float* Ap = &A[(size_t)(m0 + a_row) * 256 + k0 + a_ke];
#pragma unroll
      for (int i = 0; i < 8; ++i) av[i] = *reinterpret_cast<const f32x4*>(Ap + i * 4);
#pragma unroll
      for (int i = 0; i < 8; ++i)
        bv[i] = b_valid ? *reinterpret_cast<const f32x4*>(&W[(size_t)(k0 + b_k8 + i) * N + n0 + b_c4])
                        : f32x4{0.f, 0.f, 0.f, 0.f};
    }
    // ---- MFMA: 2 k-halves x 4x4 frags ----
#pragma unroll
    for (int kk = 0; kk < 2; ++kk) {
      const int kb = kk * 64 + lg * 16;
      s16x8 af[4], bf[4];
#pragma unroll
      for (int mf = 0; mf < 4; ++mf) {
        const int row = wr + mf * 16 + l15;
        af[mf] = *reinterpret_cast<const s16x8*>(sAb + row * 128 + (kb ^ ((row & 7) << 4)));
      }
#pragma unroll
      for (int nf = 0; nf < 4; ++nf) {
        const int col = wc + nf * 16 + l15;
        bf[nf] = *reinterpret_cast<const s16x8*>(sBb + col * 128 + (kb ^ ((col & 7) << 4)));
      }
#pragma unroll
      for (int mf = 0; mf < 4; ++mf)
#pragma unroll
        for (int nf = 0; nf < 4; ++nf)
          acc[mf][nf] = __builtin_amdgcn_mfma_f32_16x16x32_bf16(af[mf], bf[nf], acc[mf][nf], 0, 0, 0);
    }
  }

  // ---- epilogue: C[row][col], frag map col=l15, row=lg*4+j ----
#pragma unroll
  for (int nf = 0; nf < 4; ++nf) {
    const int col = n0 + wc + nf * 16 + l15;
    if (col >= N) continue;
    const float bb = bias[col];
#pragma unroll
    for (int mf = 0; mf < 4; ++mf) {
#pragma unroll
      for (int j = 0; j < 4; ++j) {
        const int row = m0 + wr + mf * 16 + lg * 4 + j;
        const size_t off = (size_t)row * N + col;
        float v = acc[mf][nf][j] + bb;
        if constexpr (RESID) v += resid[off];
        store_val(&C[off], v);
      }
    }
  }
}

// kv projections for the three concept sets: dst[10][512] = src[10][256] @ W[256][512] + b
__global__ __launch_bounds__(256) void kv_kernel(
    const float* __restrict__ unsup, const float* __restrict__ conc,
    const float* __restrict__ spat, const float* __restrict__ Wkv_c,
    const float* __restrict__ bkv_c, const float* __restrict__ Wkv_s,
    const float* __restrict__ bkv_s, float* __restrict__ kv_u,
    float* __restrict__ kv_n, float* __restrict__ kv_s)
{
  const int j = blockIdx.x;
  const float* src = (j == 0) ? unsup : ((j == 1) ? conc : spat);
  const float* W   = (j < 2) ? Wkv_c : Wkv_s;
  const float* bb  = (j < 2) ? bkv_c : bkv_s;
  float* dst       = (j == 0) ? kv_u : ((j == 1) ? kv_n : kv_s);
  __shared__ float s[2560];
  for (int i = threadIdx.x; i < 2560; i += 256) s[i] = src[i];
  __syncthreads();
  for (int o = threadIdx.x; o < 5120; o += 256) {
    const int m = o >> 9, n = o & 511;
    float acc = bb[n];
    for (int k = 0; k < 256; ++k) acc += s[m * 256 + k] * W[(size_t)k * 512 + n];
    dst[o] = acc;
  }
}

// Multi-scale deformable attention sampling, 2 queries per block.
// tid<192: per-(query,h,l,p) corner setup; gather: qi=tid>>7, h=(tid>>4)&7,
// dim-pair dp=tid&15 -> ushort2 (2 bf16) loads.
__global__ __launch_bounds__(256) void msda_kernel2(
    const float* __restrict__ off_buf, const float* __restrict__ logit_buf,
    const __hip_bfloat16* __restrict__ value, float* __restrict__ msda_out)
{
  const int bq0 = blockIdx.x * 2;
  const int b = bq0 >> 10;
  const int tid = threadIdx.x;
  __shared__ float lg[192];        // 2 x 96 logits
  __shared__ float offs[384];      // 2 x 192 offsets
  __shared__ float aw[192];
  __shared__ int   sRow[192][4];
  __shared__ float sW[192][4];
  if (tid < 192) lg[tid] = logit_buf[(size_t)bq0 * 96 + tid];
  offs[tid] = off_buf[(size_t)bq0 * 192 + tid];
  if (tid < 128) offs[256 + tid] = off_buf[(size_t)bq0 * 192 + 256 + tid];
  __syncthreads();
  if (tid < 16) {   // per (query, head) softmax over 12
    const int base = (tid >> 3) * 96 + (tid & 7) * 12;
    float mx = -1e30f;
#pragma unroll
    for (int i = 0; i < 12; ++i) mx = fmaxf(mx, lg[base + i]);
    float e[12];
    float s = 0.f;
#pragma unroll
    for (int i = 0; i < 12; ++i) { e[i] = expf(lg[base + i] - mx); s += e[i]; }
    const float inv = 1.f / s;
#pragma unroll
    for (int i = 0; i < 12; ++i) aw[base + i] = e[i] * inv;
  }
  __syncthreads();
  if (tid < 192) {
    const int WHl[3] = {64, 32, 16};
    const int St[3] = {0, 4096, 5120};
    const int qi = tid / 96, cc = tid % 96;
    const int q = (bq0 + qi) & 1023;
    const int h = cc / 12, r = cc % 12, l = r >> 2, p_ = r & 3;
    const float ox = offs[qi * 192 + h * 24 + l * 8 + p_ * 2 + 0];
    const float oy = offs[qi * 192 + h * 24 + l * 8 + p_ * 2 + 1];
    const float refx = ((q & 31) + 0.5f) * (1.0f / 32.0f);
    const float refy = ((q >> 5) + 0.5f) * (1.0f / 32.0f);
    const int WH = WHl[l];
    const float fw = (float)WH;
    const float lx = (refx + ox / fw) * fw - 0.5f;
    const float ly = (refy + oy / fw) * fw - 0.5f;
    const float fx = floorf(lx), fy = floorf(ly);
    const int x0 = (int)fx, y0 = (int)fy;
    const float dx = lx - fx, dy = ly - fy;
    const float a = aw[tid];
#pragma unroll
    for (int c = 0; c < 4; ++c) {
      const int ix = x0 + (c & 1), iy = y0 + (c >> 1);
      const float wb = ((c & 1) ? dx : 1.f - dx) * ((c >> 1) ? dy : 1.f - dy);
      const bool valid = (ix >= 0) && (ix < WH) && (iy >= 0) && (iy < WH);
      const int cx = min(max(ix, 0), WH - 1);
      const int cy = min(max(iy, 0), WH - 1);
      sRow[tid][c] = St[l] + cy * WH + cx;
      sW[tid][c] = valid ? wb * a : 0.f;
    }
  }
  __syncthreads();
  const int qi = tid >> 7;
  const int h = (tid >> 4) & 7;
  const int dp = tid & 15;
  const __hip_bfloat16* vb = value + (size_t)b * (5376 * 256) + h * 32 + dp * 2;
  float ax = 0.f, ay = 0.f;
#pragma unroll
  for (int s = 0; s < 12; ++s) {
    const int cc = qi * 96 + h * 12 + s;
#pragma unroll
    for (int c = 0; c < 4; ++c) {
      const float wgt = sW[cc][c];
      const unsigned int vv =
          *reinterpret_cast<const unsigned int*>(vb + (size_t)sRow[cc][c] * 256);
      ax += wgt * __builtin_bit_cast(float, vv << 16);
      ay += wgt * __builtin_bit_cast(float, vv & 0xFFFF0000u);
    }
  }
  float2 o2 = {ax, ay};
  *reinterpret_cast<float2*>(&msda_out[(size_t)(bq0 + qi) * 256 + h * 32 + dp * 2]) = o2;
}

// cls cross-attention (unsup + normal concepts). One 64-thread block per b.
__global__ __launch_bounds__(64) void cls_attn_kernel(
    const float* __restrict__ x_cls, const float* __restrict__ Wq_c,
    const float* __restrict__ bq_c, const float* __restrict__ kv_u,
    const float* __restrict__ kv_n, float* __restrict__ o_un,
    float* __restrict__ attn_u_out, float* __restrict__ attn_n_out)
{
  const int b = blockIdx.x;
  const int lane = threadIdx.x;
  __shared__ float xr[256];
  *reinterpret_cast<float4*>(&xr[lane * 4]) =
      *reinterpret_cast<const float4*>(&x_cls[(size_t)b * 256 + lane * 4]);
  __syncthreads();
  float4 q4 = *reinterpret_cast<const float4*>(&bq_c[lane * 4]);
  for (int k = 0; k < 256; ++k) {
    const float xk = xr[k];
    const float4 w = *reinterpret_cast<const float4*>(&Wq_c[(size_t)k * 256 + lane * 4]);
    q4.x += xk * w.x; q4.y += xk * w.y; q4.z += xk * w.z; q4.w += xk * w.w;
  }
  const float scale = 0.08838834764831845f;  // 1/sqrt(128)
  float4 osum = {0.f, 0.f, 0.f, 0.f};
  for (int cs = 0; cs < 2; ++cs) {
    const float* kv = cs ? kv_n : kv_u;
    float* aout = cs ? attn_n_out : attn_u_out;
    float attn[10];
    float mx = -1e30f;
#pragma unroll
    for (int m = 0; m < 10; ++m) {
      const float4 k4 = *reinterpret_cast<const float4*>(&kv[m * 512 + lane * 4]);
      float p = q4.x * k4.x + q4.y * k4.y + q4.z * k4.z + q4.w * k4.w;
      p += __shfl_xor(p, 1);  p += __shfl_xor(p, 2);  p += __shfl_xor(p, 4);
      p += __shfl_xor(p, 8);  p += __shfl_xor(p, 16);
      attn[m] = p * scale;
      mx = fmaxf(mx, attn[m]);
    }
    float s = 0.f;
#pragma unroll
    for (int m = 0; m < 10; ++m) { attn[m] = expf(attn[m] - mx); s += attn[m]; }
    const float inv = 1.f / s;
#pragma unroll
    for (int m = 0; m < 10; ++m) {
      attn[m] *= inv;
      const float am = 0.5f * (attn[m] + __shfl_xor(attn[m], 32));
      if (lane == m) aout[b * 10 + m] = am;
      const float4 v4 = *reinterpret_cast<const float4*>(&kv[m * 512 + 256 + lane * 4]);
      osum.x += attn[m] * v4.x; osum.y += attn[m] * v4.y;
      osum.z += attn[m] * v4.z; osum.w += attn[m] * v4.w;
    }
  }
  *reinterpret_cast<float4*>(&o_un[(size_t)b * 256 + lane * 4]) = osum;
}

// spatial cross-attention: one wave per query (4 waves/block).
__global__ __launch_bounds__(256) void spatial_attn_kernel(
    const float* __restrict__ q_s, const float* __restrict__ kv_s,
    float* __restrict__ o_s, float* __restrict__ attn_out)
{
  const int lane = threadIdx.x & 63;
  const int qg = blockIdx.x * 4 + (threadIdx.x >> 6);
  const float4 q4 = *reinterpret_cast<const float4*>(&q_s[(size_t)qg * 256 + lane * 4]);
  const float scale = 0.08838834764831845f;
  float attn[10];
  float mx = -1e30f;
#pragma unroll
  for (int m = 0; m < 10; ++m) {
    const float4 k4 = *reinterpret_cast<const float4*>(&kv_s[m * 512 + lane * 4]);
    float p = q4.x * k4.x + q4.y * k4.y + q4.z * k4.z + q4.w * k4.w;
    p += __shfl_xor(p, 1);  p += __shfl_xor(p, 2);  p += __shfl_xor(p, 4);
    p += __shfl_xor(p, 8);  p += __shfl_xor(p, 16);
    attn[m] = p * scale;
    mx = fmaxf(mx, attn[m]);
  }
  float s = 0.f;
#pragma unroll
  for (int m = 0; m < 10; ++m) { attn[m] = expf(attn[m] - mx); s += attn[m]; }
  const float inv = 1.f / s;
  float4 o4 = {0.f, 0.f, 0.f, 0.f};
#pragma unroll
  for (int m = 0; m < 10; ++m) {
    attn[m] *= inv;
    const float am = 0.5f * (attn[m] + __shfl_xor(attn[m], 32));
    if (lane == m) attn_out[(size_t)qg * 10 + m] = am;
    const float4 v4 = *reinterpret_cast<const float4*>(&kv_s[m * 512 + 256 + lane * 4]);
    o4.x += attn[m] * v4.x; o4.y += attn[m] * v4.y;
    o4.z += attn[m] * v4.z; o4.w += attn[m] * v4.w;
  }
  *reinterpret_cast<float4*>(&o_s[(size_t)qg * 256 + lane * 4]) = o4;
}

// partial reduction of o_s over queries
__global__ __launch_bounds__(256) void reduce_os_kernel(
    const float* __restrict__ o_s, float* __restrict__ o_spart)
{
  const int b = blockIdx.x, ch = blockIdx.y, d = threadIdx.x;
  const float* p = o_s + ((size_t)b * 1024 + ch * 64) * 256 + d;
  float s = 0.f;
  for (int i = 0; i < 64; ++i) s += p[(size_t)i * 256];
  o_spart[((size_t)b * 16 + ch) * 256 + d] = s;
}

// final classification head
__global__ __launch_bounds__(256) void final_out_kernel(
    const float* __restrict__ o_un, const float* __restrict__ o_spart,
    const float* __restrict__ Wp_c, const float* __restrict__ bp_c,
    const float* __restrict__ Wp_s, const float* __restrict__ bp_s,
    float* __restrict__ out)
{
  const int b = blockIdx.x, c = threadIdx.x;
  __shared__ float ou[256], os[256];
  float s = 0.f;
  for (int ch = 0; ch < 16; ++ch) s += o_spart[((size_t)b * 16 + ch) * 256 + c];
  ou[c] = o_un[(size_t)b * 256 + c];
  os[c] = s * (1.0f / 1024.0f);
  __syncthreads();
  if (c < 200) {
    float acc = 2.f * bp_c[c] + bp_s[c];
    for (int d = 0; d < 256; ++d)
      acc += ou[d] * Wp_c[d * 200 + c] + os[d] * Wp_s[d * 200 + c];
    out[b * 200 + c] = acc;
  }
}

extern "C" void kernel_launch(void* const* d_in, const int* in_sizes, int n_in,
                              void* d_out, int out_size, void* d_ws, size_t ws_size,
                              hipStream_t stream)
{
  const float* query  = (const float*)d_in[0];
  const float* feats  = (const float*)d_in[1];
  const float* x_cls  = (const float*)d_in[2];
  const float* W_off  = (const float*)d_in[3];
  const float* b_off  = (const float*)d_in[4];
  const float* W_attn = (const float*)d_in[5];
  const float* b_attn = (const float*)d_in[6];
  const float* W_val  = (const float*)d_in[7];
  const float* b_val  = (const float*)d_in[8];
  const float* W_out  = (const float*)d_in[9];
  const float* b_out  = (const float*)d_in[10];
  const float* unsup  = (const float*)d_in[11];
  const float* conc   = (const float*)d_in[12];
  const float* spat   = (const float*)d_in[13];
  const float* Wq_c   = (const float*)d_in[14];
  const float* bq_c   = (const float*)d_in[15];
  const float* Wkv_c  = (const float*)d_in[16];
  const float* bkv_c  = (const float*)d_in[17];
  const float* Wp_c   = (const float*)d_in[18];
  const float* bp_c   = (const float*)d_in[19];
  const float* Wq_s   = (const float*)d_in[20];
  const float* bq_s   = (const float*)d_in[21];
  const float* Wkv_s  = (const float*)d_in[22];
  const float* bkv_s  = (const float*)d_in[23];
  const float* Wp_s   = (const float*)d_in[24];
  const float* bp_s   = (const float*)d_in[25];
  float* out = (float*)d_out;

  const int B = 32, LQ = 1024, LIN = 5376, D = 256;
  const int MQ = B * LQ;    // 32768
  const int MV = B * LIN;   // 172032

  __hip_bfloat16* value = (__hip_bfloat16*)d_ws;
  const size_t val_bytes = (size_t)MV * D * sizeof(__hip_bfloat16);
  float* fbase     = (float*)((char*)d_ws + val_bytes);
  float* off_buf   = fbase;
  float* logit_buf = off_buf + (size_t)MQ * 192;
  float* msda_raw  = logit_buf + (size_t)MQ * 96;
  float* x         = msda_raw + (size_t)MQ * 256;
  float* kv_u      = x + (size_t)MQ * 256;
  float* kv_n      = kv_u + 5120;
  float* kv_s      = kv_n + 5120;
  float* o_un      = kv_s + 5120;
  float* o_spart   = o_un + B * 256;
  // reuse of the (dead) value region after msda_kernel2:
  float* q_s = (float*)d_ws;
  float* o_s = q_s + (size_t)MQ * 256;

  dim3 blk(256);
  // value = feats @ W_val + b_val  (bf16 out)
  gemm_mfma<__hip_bfloat16, false><<<dim3(MV / 128, 2), blk, 0, stream>>>(
      feats, W_val, b_val, nullptr, value, MV, 256, 256);
  // off = query @ W_off + b_off  (N=192, masked)
  gemm_mfma<float, false><<<dim3(MQ / 128, 2), blk, 0, stream>>>(
      query, W_off, b_off, nullptr, off_buf, MQ, 192, 256);
  // logits = query @ W_attn + b_attn  (N=96, masked)
  gemm_mfma<float, false><<<dim3(MQ / 128, 1), blk, 0, stream>>>(
      query, W_attn, b_attn, nullptr, logit_buf, MQ, 96, 256);
  // kv projections
  kv_kernel<<<dim3(3), blk, 0, stream>>>(unsup, conc, spat, Wkv_c, bkv_c,
                                         Wkv_s, bkv_s, kv_u, kv_n, kv_s);
  // deformable sampling (2 queries / block)
  msda_kernel2<<<dim3(MQ / 2), blk, 0, stream>>>(off_buf, logit_buf, value, msda_raw);
  // x = query + msda_raw @ W_out + b_out
  gemm_mfma<float, true><<<dim3(MQ / 128, 2), blk, 0, stream>>>(
      msda_raw, W_out, b_out, query, x, MQ, 256, 256);
  // q_s = x @ Wq_s + bq_s  (overwrites dead value region)
  gemm_mfma<float, false><<<dim3(MQ / 128, 2), blk, 0, stream>>>(
      x, Wq_s, bq_s, nullptr, q_s, MQ, 256, 256);
  // cls branch
  cls_attn_kernel<<<dim3(B), dim3(64), 0, stream>>>(
      x_cls, Wq_c, bq_c, kv_u, kv_n, o_un, out + 6400, out + 6720);
  // spatial attention
  spatial_attn_kernel<<<dim3(MQ / 4), blk, 0, stream>>>(q_s, kv_s, o_s, out + 7040);
  // mean over queries + final head
  reduce_os_kernel<<<dim3(B, 16), blk, 0, stream>>>(o_s, o_spart);
  final_out_kernel<<<dim3(B), blk, 0, stream>>>(o_un, o_spart, Wp_c, bp_c,
                                                Wp_s, bp_s, out);
}

// Round 3
// 432.640 us; speedup vs baseline: 2.0950x; 1.2568x over previous
//
#include <hip/hip_runtime.h>
#include <hip/hip_bf16.h>

// ---------------------------------------------------------------------------
// B=32, LQ=1024, LIN=5376, D=256, NH=8, L=3, P=4, DH=32, NH_CA=2, M=10, NCLS=200
// Outputs (f32): out[6400) | attn_u[320) | attn_n[320) | attn_s[327680)
// Spatial branch is algebraically folded:
//   logits(b,q)[20] = query@WL + msda@WL2 + cL   (WL=scale*Wq_s@K^T, WL2=W_out@WL)
//   attn_s = mean_h softmax_h;  out_s.mean(q) = (sum_m abar[h,m] V[h,m])@Wp_s
// ---------------------------------------------------------------------------

typedef __attribute__((ext_vector_type(8))) short s16x8;
typedef __attribute__((ext_vector_type(4))) float f32x4;

__device__ __forceinline__ void store_val(float* p, float v) { *p = v; }
__device__ __forceinline__ void store_val(__hip_bfloat16* p, float v) { *p = __float2bfloat16(v); }

__device__ __forceinline__ unsigned short f2bf(float x) {
  unsigned int u = __builtin_bit_cast(unsigned int, x);
  u += 0x7FFFu + ((u >> 16) & 1u);  // RNE
  return (unsigned short)(u >> 16);
}
__device__ __forceinline__ float bf2f(unsigned short u) {
  return __builtin_bit_cast(float, (unsigned int)u << 16);
}

// ---------------------------------------------------------------------------
// bf16-MFMA GEMM, coalesced A staging. C[M,N] = A[M,256] @ W[256,N] + bias.
// BM=128, BN=128, BK=64; 4 waves (2x2), wave tile 64x64. M%128==0, K==256.
// ---------------------------------------------------------------------------
template <typename OT>
__global__ __launch_bounds__(256, 2) void gemm_mfma(
    const float* __restrict__ A, const float* __restrict__ W,
    const float* __restrict__ bias, OT* __restrict__ C,
    int M, int N, int K /* == 256 */)
{
  __shared__ unsigned short sA[128 * 64];
  __shared__ unsigned short sB[128 * 64];
  char* sAb = (char*)sA;
  char* sBb = (char*)sB;

  const int tid = threadIdx.x;
  const int m0 = blockIdx.x * 128;
  const int n0 = blockIdx.y * 128;
  const int lane = tid & 63;
  const int w = tid >> 6;
  const int wr = (w >> 1) * 64, wc = (w & 1) * 64;
  const int l15 = lane & 15;
  const int lg = lane >> 4;

  // A staging: it=0..7 -> row = it*16 + (tid>>4), f32 col = (tid&15)*4
  // each wave-instruction reads 4 rows x 256B contiguous (16 full 64B lines)
  const int a_row = tid >> 4;
  const int a_c4 = (tid & 15) * 4;
  const int a_swz = (a_row & 7) << 4;
  // B staging: k = (tid>>5)*8 + i, f32 col = (tid&31)*4 (512B contiguous/row)
  const int b_k8 = (tid >> 5) * 8;
  const int b_c4 = (tid & 31) * 4;
  const bool b_valid = (n0 + b_c4) < N;

  f32x4 acc[4][4] = {};
  f32x4 av[8], bv[8];

  const float* Abase = A + (size_t)(m0 + a_row) * K + a_c4;

  // prologue (k0 = 0)
#pragma unroll
  for (int it = 0; it < 8; ++it)
    av[it] = *reinterpret_cast<const f32x4*>(Abase + (size_t)it * 16 * K);
#pragma unroll
  for (int i = 0; i < 8; ++i)
    bv[i] = b_valid ? *reinterpret_cast<const f32x4*>(&W[(size_t)(b_k8 + i) * N + n0 + b_c4])
                    : f32x4{0.f, 0.f, 0.f, 0.f};

#pragma unroll
  for (int ks = 0; ks < 4; ++ks) {
    __syncthreads();
    // stage A (bf16 pack, 8B swizzled writes)
#pragma unroll
    for (int it = 0; it < 8; ++it) {
      uint2 p;
      p.x = (unsigned)f2bf(av[it][0]) | ((unsigned)f2bf(av[it][1]) << 16);
      p.y = (unsigned)f2bf(av[it][2]) | ((unsigned)f2bf(av[it][3]) << 16);
      const int off = (it * 16 + a_row) * 128 + ((a_c4 * 2) ^ a_swz);
      *reinterpret_cast<uint2*>(sAb + off) = p;
    }
    // stage B transposed: col j holds k8..k8+7 packed (16B writes)
#pragma unroll
    for (int j = 0; j < 4; ++j) {
      uint4 p;
      p.x = (unsigned)f2bf(bv[0][j]) | ((unsigned)f2bf(bv[1][j]) << 16);
      p.y = (unsigned)f2bf(bv[2][j]) | ((unsigned)f2bf(bv[3][j]) << 16);
      p.z = (unsigned)f2bf(bv[4][j]) | ((unsigned)f2bf(bv[5][j]) << 16);
      p.w = (unsigned)f2bf(bv[6][j]) | ((unsigned)f2bf(bv[7][j]) << 16);
      const int col = b_c4 + j;
      const int off = col * 128 + ((b_k8 * 2) ^ ((col & 7) << 4));
      *reinterpret_cast<uint4*>(sBb + off) = p;
    }
    __syncthreads();
    // issue next-tile global loads before the MFMA section
    if (ks < 3) {
      const int k0 = (ks + 1) * 64;
#pragma unroll
      for (int it = 0; it < 8; ++it)
        av[it] = *reinterpret_cast<const f32x4*>(Abase + k0 + (size_t)it * 16 * K);
#pragma unroll
      for (int i = 0; i < 8; ++i)
        bv[i] = b_valid ? *reinterpret_cast<const f32x4*>(&W[(size_t)(k0 + b_k8 + i) * N + n0 + b_c4])
                        : f32x4{0.f, 0.f, 0.f, 0.f};
    }
    // MFMA: 2 k-halves x 4x4 frags
#pragma unroll
    for (int kk = 0; kk < 2; ++kk) {
      const int kb = kk * 64 + lg * 16;
      s16x8 af[4], bf[4];
#pragma unroll
      for (int mf = 0; mf < 4; ++mf) {
        const int row = wr + mf * 16 + l15;
        af[mf] = *reinterpret_cast<const s16x8*>(sAb + row * 128 + (kb ^ ((row & 7) << 4)));
      }
#pragma unroll
      for (int nf = 0; nf < 4; ++nf) {
        const int col = wc + nf * 16 + l15;
        bf[nf] = *reinterpret_cast<const s16x8*>(sBb + col * 128 + (kb ^ ((col & 7) << 4)));
      }
#pragma unroll
      for (int mf = 0; mf < 4; ++mf)
#pragma unroll
        for (int nf = 0; nf < 4; ++nf)
          acc[mf][nf] = __builtin_amdgcn_mfma_f32_16x16x32_bf16(af[mf], bf[nf], acc[mf][nf], 0, 0, 0);
    }
  }

  // epilogue: col=l15, row=lg*4+j
#pragma unroll
  for (int nf = 0; nf < 4; ++nf) {
    const int col = n0 + wc + nf * 16 + l15;
    if (col >= N) continue;
    const float bb = bias[col];
#pragma unroll
    for (int mf = 0; mf < 4; ++mf) {
#pragma unroll
      for (int j = 0; j < 4; ++j) {
        const int row = m0 + wr + mf * 16 + lg * 4 + j;
        store_val(&C[(size_t)row * N + col], acc[mf][nf][j] + bb);
      }
    }
  }
}

// pack [W_off | W_attn] -> Wpack[256][288], [b_off | b_attn] -> bpack[288]
__global__ __launch_bounds__(256) void pack_kernel(
    const float* __restrict__ W_off, const float* __restrict__ b_off,
    const float* __restrict__ W_attn, const float* __restrict__ b_attn,
    float* __restrict__ Wpack, float* __restrict__ bpack)
{
  const int idx = blockIdx.x * 256 + threadIdx.x;
  if (idx < 256 * 288) {
    const int k = idx / 288, j = idx % 288;
    Wpack[idx] = (j < 192) ? W_off[k * 192 + j] : W_attn[k * 96 + (j - 192)];
  }
  if (idx < 288) bpack[idx] = (idx < 192) ? b_off[idx] : b_attn[idx - 192];
}

// kv projections: dst[10][512] = src[10][256] @ W[256][512] + b
__global__ __launch_bounds__(256) void kv_kernel(
    const float* __restrict__ unsup, const float* __restrict__ conc,
    const float* __restrict__ spat, const float* __restrict__ Wkv_c,
    const float* __restrict__ bkv_c, const float* __restrict__ Wkv_s,
    const float* __restrict__ bkv_s, float* __restrict__ kv_u,
    float* __restrict__ kv_n, float* __restrict__ kv_s)
{
  const int j = blockIdx.x;
  const float* src = (j == 0) ? unsup : ((j == 1) ? conc : spat);
  const float* W   = (j < 2) ? Wkv_c : Wkv_s;
  const float* bb  = (j < 2) ? bkv_c : bkv_s;
  float* dst       = (j == 0) ? kv_u : ((j == 1) ? kv_n : kv_s);
  __shared__ float s[2560];
  for (int i = threadIdx.x; i < 2560; i += 256) s[i] = src[i];
  __syncthreads();
  for (int o = threadIdx.x; o < 5120; o += 256) {
    const int m = o >> 9, n = o & 511;
    float acc = bb[n];
    for (int k = 0; k < 256; ++k) acc += s[m * 256 + k] * W[(size_t)k * 512 + n];
    dst[o] = acc;
  }
}

// prep: per concept-column j=(h*10+m): WLt[j][256], WL2t[j][256], cL[j]
// WL[d] = sum_e Wq_s[d][h*128+e]*k[e];  WL2[t] = sum_d W_out[t][d]*WL[d]
// cL = sum_d b_out[d]*WL[d] + sum_e bq_s[h*128+e]*k[e]; all scaled by 1/sqrt(128)
__global__ __launch_bounds__(256) void prep_kernel(
    const float* __restrict__ Wq_s, const float* __restrict__ bq_s,
    const float* __restrict__ W_out, const float* __restrict__ b_out,
    const float* __restrict__ kv_s, float* __restrict__ WLt,
    float* __restrict__ WL2t, float* __restrict__ cL)
{
  const int j = blockIdx.x;
  const int h = j / 10, m = j % 10;
  const int tid = threadIdx.x;
  __shared__ float kk[128], wl[256], bred[256];
  if (tid < 128) kk[tid] = kv_s[m * 512 + h * 128 + tid];
  __syncthreads();
  float acc = 0.f;
  for (int e = 0; e < 128; ++e) acc += Wq_s[(size_t)tid * 256 + h * 128 + e] * kk[e];
  wl[tid] = acc;
  __syncthreads();
  float acc2 = 0.f;
  for (int t = 0; t < 256; ++t) acc2 += W_out[(size_t)tid * 256 + t] * wl[t];
  const float scale = 0.08838834764831845f;
  WLt[j * 256 + tid] = scale * acc;
  WL2t[j * 256 + tid] = scale * acc2;
  bred[tid] = b_out[tid] * wl[tid] + ((tid < 128) ? bq_s[h * 128 + tid] * kk[tid] : 0.f);
  __syncthreads();
  for (int s = 128; s > 0; s >>= 1) {
    if (tid < s) bred[tid] += bred[tid + s];
    __syncthreads();
  }
  if (tid == 0) cL[j] = scale * bred[0];
}

// MSDA sampling, 2 queries/block, reads packed offlog (stride 288), bf16 out.
__global__ __launch_bounds__(256) void msda_kernel2(
    const float* __restrict__ offlog, const __hip_bfloat16* __restrict__ value,
    __hip_bfloat16* __restrict__ msda_out)
{
  const int bq0 = blockIdx.x * 2;
  const int b = bq0 >> 10;
  const int tid = threadIdx.x;
  __shared__ float lg[192];
  __shared__ float offs[384];
  __shared__ float aw[192];
  __shared__ int   sRow[192][4];
  __shared__ float sW[192][4];
  if (tid < 192) {
    const int qi = tid / 96;
    lg[tid] = offlog[(size_t)(bq0 + qi) * 288 + 192 + (tid % 96)];
  }
  for (int i = tid; i < 384; i += 256) {
    const int qi = i / 192;
    offs[i] = offlog[(size_t)(bq0 + qi) * 288 + (i % 192)];
  }
  __syncthreads();
  if (tid < 16) {
    const int base = (tid >> 3) * 96 + (tid & 7) * 12;
    float mx = -1e30f;
#pragma unroll
    for (int i = 0; i < 12; ++i) mx = fmaxf(mx, lg[base + i]);
    float e[12];
    float s = 0.f;
#pragma unroll
    for (int i = 0; i < 12; ++i) { e[i] = expf(lg[base + i] - mx); s += e[i]; }
    const float inv = 1.f / s;
#pragma unroll
    for (int i = 0; i < 12; ++i) aw[base + i] = e[i] * inv;
  }
  __syncthreads();
  if (tid < 192) {
    const int WHl[3] = {64, 32, 16};
    const int St[3] = {0, 4096, 5120};
    const int qi = tid / 96, cc = tid % 96;
    const int q = (bq0 + qi) & 1023;
    const int h = cc / 12, r = cc % 12, l = r >> 2, p_ = r & 3;
    const float ox = offs[qi * 192 + h * 24 + l * 8 + p_ * 2 + 0];
    const float oy = offs[qi * 192 + h * 24 + l * 8 + p_ * 2 + 1];
    const float refx = ((q & 31) + 0.5f) * (1.0f / 32.0f);
    const float refy = ((q >> 5) + 0.5f) * (1.0f / 32.0f);
    const int WH = WHl[l];
    const float fw = (float)WH;
    const float lx = (refx + ox / fw) * fw - 0.5f;
    const float ly = (refy + oy / fw) * fw - 0.5f;
    const float fx = floorf(lx), fy = floorf(ly);
    const int x0 = (int)fx, y0 = (int)fy;
    const float dx = lx - fx, dy = ly - fy;
    const float a = aw[tid];
#pragma unroll
    for (int c = 0; c < 4; ++c) {
      const int ix = x0 + (c & 1), iy = y0 + (c >> 1);
      const float wb = ((c & 1) ? dx : 1.f - dx) * ((c >> 1) ? dy : 1.f - dy);
      const bool valid = (ix >= 0) && (ix < WH) && (iy >= 0) && (iy < WH);
      const int cx = min(max(ix, 0), WH - 1);
      const int cy = min(max(iy, 0), WH - 1);
      sRow[tid][c] = St[l] + cy * WH + cx;
      sW[tid][c] = valid ? wb * a : 0.f;
    }
  }
  __syncthreads();
  const int qi = tid >> 7;
  const int h = (tid >> 4) & 7;
  const int dp = tid & 15;
  const __hip_bfloat16* vb = value + (size_t)b * (5376 * 256) + h * 32 + dp * 2;
  float ax = 0.f, ay = 0.f;
#pragma unroll
  for (int s = 0; s < 12; ++s) {
    const int cc = qi * 96 + h * 12 + s;
#pragma unroll
    for (int c = 0; c < 4; ++c) {
      const float wgt = sW[cc][c];
      const unsigned int vv =
          *reinterpret_cast<const unsigned int*>(vb + (size_t)sRow[cc][c] * 256);
      ax += wgt * __builtin_bit_cast(float, vv << 16);
      ay += wgt * __builtin_bit_cast(float, vv & 0xFFFF0000u);
    }
  }
  const unsigned int pk = (unsigned)f2bf(ax) | ((unsigned)f2bf(ay) << 16);
  *reinterpret_cast<unsigned int*>(
      (unsigned short*)msda_out + (size_t)(bq0 + qi) * 256 + h * 32 + dp * 2) = pk;
}

// fused spatial branch: logits = query@WLt + msda@WL2t + cL -> per-head
// softmax -> attn_s output + per-block abar partial sums.
// 128 rows/block, 2 threads/row (k-halves).
__global__ __launch_bounds__(256) void spatial_kernel(
    const float* __restrict__ query, const __hip_bfloat16* __restrict__ msda,
    const float* __restrict__ WLt, const float* __restrict__ WL2t,
    const float* __restrict__ cL, float* __restrict__ attn_out,
    float* __restrict__ partial)
{
  __shared__ float wls[20][256];
  __shared__ float wl2s[20][256];
  __shared__ float red[128][20];
  const int tid = threadIdx.x;
  for (int i = tid; i < 5120; i += 256) {
    wls[i >> 8][i & 255] = WLt[i];
    wl2s[i >> 8][i & 255] = WL2t[i];
  }
  const int row_local = tid >> 1;
  const int half = tid & 1;
  const int row = blockIdx.x * 128 + row_local;
  float acc[20];
#pragma unroll
  for (int c = 0; c < 20; ++c) acc[c] = half ? 0.f : cL[c];
  __syncthreads();

  const float* qp = &query[(size_t)row * 256 + half * 128];
  const unsigned short* mp = (const unsigned short*)msda + (size_t)row * 256 + half * 128;
  const int kbase = half * 128;
  for (int k = 0; k < 128; k += 4) {
    const f32x4 q4 = *reinterpret_cast<const f32x4*>(qp + k);
    const uint2 mm = *reinterpret_cast<const uint2*>(mp + k);
    const float m0 = bf2f((unsigned short)mm.x);
    const float m1 = bf2f((unsigned short)(mm.x >> 16));
    const float m2 = bf2f((unsigned short)mm.y);
    const float m3 = bf2f((unsigned short)(mm.y >> 16));
#pragma unroll
    for (int c = 0; c < 20; ++c) {
      const f32x4 w4 = *reinterpret_cast<const f32x4*>(&wls[c][kbase + k]);
      const f32x4 v4 = *reinterpret_cast<const f32x4*>(&wl2s[c][kbase + k]);
      acc[c] += q4.x * w4.x + q4.y * w4.y + q4.z * w4.z + q4.w * w4.w
              + m0 * v4.x + m1 * v4.y + m2 * v4.z + m3 * v4.w;
    }
  }
  if (half == 1) {
#pragma unroll
    for (int c = 0; c < 20; ++c) red[row_local][c] = acc[c];
  }
  __syncthreads();
  if (half == 0) {
    float a[20];
#pragma unroll
    for (int c = 0; c < 20; ++c) a[c] = acc[c] + red[row_local][c];
#pragma unroll
    for (int h = 0; h < 2; ++h) {
      float mx = -1e30f;
#pragma unroll
      for (int m = 0; m < 10; ++m) mx = fmaxf(mx, a[h * 10 + m]);
      float s = 0.f;
#pragma unroll
      for (int m = 0; m < 10; ++m) { a[h * 10 + m] = expf(a[h * 10 + m] - mx); s += a[h * 10 + m]; }
      const float inv = 1.f / s;
#pragma unroll
      for (int m = 0; m < 10; ++m) a[h * 10 + m] *= inv;
    }
#pragma unroll
    for (int m = 0; m < 10; ++m)
      attn_out[(size_t)row * 10 + m] = 0.5f * (a[m] + a[10 + m]);
#pragma unroll
    for (int c = 0; c < 20; ++c) red[row_local][c] = a[c];
  }
  __syncthreads();
  if (tid < 20) {
    float s = 0.f;
    for (int r = 0; r < 128; ++r) s += red[r][tid];
    partial[blockIdx.x * 20 + tid] = s;
  }
}

// cls cross-attention (unsup + normal concepts). One 64-thread block per b.
__global__ __launch_bounds__(64) void cls_attn_kernel(
    const float* __restrict__ x_cls, const float* __restrict__ Wq_c,
    const float* __restrict__ bq_c, const float* __restrict__ kv_u,
    const float* __restrict__ kv_n, float* __restrict__ o_un,
    float* __restrict__ attn_u_out, float* __restrict__ attn_n_out)
{
  const int b = blockIdx.x;
  const int lane = threadIdx.x;
  __shared__ float xr[256];
  *reinterpret_cast<float4*>(&xr[lane * 4]) =
      *reinterpret_cast<const float4*>(&x_cls[(size_t)b * 256 + lane * 4]);
  __syncthreads();
  float4 q4 = *reinterpret_cast<const float4*>(&bq_c[lane * 4]);
  for (int k = 0; k < 256; ++k) {
    const float xk = xr[k];
    const float4 w = *reinterpret_cast<const float4*>(&Wq_c[(size_t)k * 256 + lane * 4]);
    q4.x += xk * w.x; q4.y += xk * w.y; q4.z += xk * w.z; q4.w += xk * w.w;
  }
  const float scale = 0.08838834764831845f;
  float4 osum = {0.f, 0.f, 0.f, 0.f};
  for (int cs = 0; cs < 2; ++cs) {
    const float* kv = cs ? kv_n : kv_u;
    float* aout = cs ? attn_n_out : attn_u_out;
    float attn[10];
    float mx = -1e30f;
#pragma unroll
    for (int m = 0; m < 10; ++m) {
      const float4 k4 = *reinterpret_cast<const float4*>(&kv[m * 512 + lane * 4]);
      float p = q4.x * k4.x + q4.y * k4.y + q4.z * k4.z + q4.w * k4.w;
      p += __shfl_xor(p, 1);  p += __shfl_xor(p, 2);  p += __shfl_xor(p, 4);
      p += __shfl_xor(p, 8);  p += __shfl_xor(p, 16);
      attn[m] = p * scale;
      mx = fmaxf(mx, attn[m]);
    }
    float s = 0.f;
#pragma unroll
    for (int m = 0; m < 10; ++m) { attn[m] = expf(attn[m] - mx); s += attn[m]; }
    const float inv = 1.f / s;
#pragma unroll
    for (int m = 0; m < 10; ++m) {
      attn[m] *= inv;
      const float am = 0.5f * (attn[m] + __shfl_xor(attn[m], 32));
      if (lane == m) aout[b * 10 + m] = am;
      const float4 v4 = *reinterpret_cast<const float4*>(&kv[m * 512 + 256 + lane * 4]);
      osum.x += attn[m] * v4.x; osum.y += attn[m] * v4.y;
      osum.z += attn[m] * v4.z; osum.w += attn[m] * v4.w;
    }
  }
  *reinterpret_cast<float4*>(&o_un[(size_t)b * 256 + lane * 4]) = osum;
}

// final head: abar from partials -> o_sbar via V_s -> out[b][200]
__global__ __launch_bounds__(256) void final_out_kernel(
    const float* __restrict__ o_un, const float* __restrict__ partial,
    const float* __restrict__ kv_s, const float* __restrict__ Wp_c,
    const float* __restrict__ bp_c, const float* __restrict__ Wp_s,
    const float* __restrict__ bp_s, float* __restrict__ out)
{
  const int b = blockIdx.x, c = threadIdx.x;
  __shared__ float ou[256], os[256], abar[20];
  if (c < 20) {
    float s = 0.f;
    for (int ch = 0; ch < 8; ++ch) s += partial[(b * 8 + ch) * 20 + c];
    abar[c] = s * (1.0f / 1024.0f);
  }
  ou[c] = o_un[(size_t)b * 256 + c];
  __syncthreads();
  const int h = c >> 7, d = c & 127;
  float s = 0.f;
#pragma unroll
  for (int m = 0; m < 10; ++m) s += abar[h * 10 + m] * kv_s[m * 512 + 256 + h * 128 + d];
  os[c] = s;
  __syncthreads();
  if (c < 200) {
    float acc = 2.f * bp_c[c] + bp_s[c];
    for (int dd = 0; dd < 256; ++dd)
      acc += ou[dd] * Wp_c[dd * 200 + c] + os[dd] * Wp_s[dd * 200 + c];
    out[b * 200 + c] = acc;
  }
}

extern "C" void kernel_launch(void* const* d_in, const int* in_sizes, int n_in,
                              void* d_out, int out_size, void* d_ws, size_t ws_size,
                              hipStream_t stream)
{
  const float* query  = (const float*)d_in[0];
  const float* feats  = (const float*)d_in[1];
  const float* x_cls  = (const float*)d_in[2];
  const float* W_off  = (const float*)d_in[3];
  const float* b_off  = (const float*)d_in[4];
  const float* W_attn = (const float*)d_in[5];
  const float* b_attn = (const float*)d_in[6];
  const float* W_val  = (const float*)d_in[7];
  const float* b_val  = (const float*)d_in[8];
  const float* W_out  = (const float*)d_in[9];
  const float* b_out  = (const float*)d_in[10];
  const float* unsup  = (const float*)d_in[11];
  const float* conc   = (const float*)d_in[12];
  const float* spat   = (const float*)d_in[13];
  const float* Wq_c   = (const float*)d_in[14];
  const float* bq_c   = (const float*)d_in[15];
  const float* Wkv_c  = (const float*)d_in[16];
  const float* bkv_c  = (const float*)d_in[17];
  const float* Wp_c   = (const float*)d_in[18];
  const float* bp_c   = (const float*)d_in[19];
  const float* Wq_s   = (const float*)d_in[20];
  const float* bq_s   = (const float*)d_in[21];
  const float* Wkv_s  = (const float*)d_in[22];
  const float* bkv_s  = (const float*)d_in[23];
  const float* Wp_s   = (const float*)d_in[24];
  const float* bp_s   = (const float*)d_in[25];
  float* out = (float*)d_out;

  const int B = 32, LQ = 1024, LIN = 5376;
  const int MQ = B * LQ;    // 32768
  const int MV = B * LIN;   // 172032

  // workspace layout (~143 MB)
  char* p = (char*)d_ws;
  __hip_bfloat16* value = (__hip_bfloat16*)p;   p += (size_t)MV * 256 * 2;
  float* offlog   = (float*)p;                  p += (size_t)MQ * 288 * 4;
  __hip_bfloat16* msda = (__hip_bfloat16*)p;    p += (size_t)MQ * 256 * 2;
  float* kv_u     = (float*)p;                  p += 5120 * 4;
  float* kv_n     = (float*)p;                  p += 5120 * 4;
  float* kv_s     = (float*)p;                  p += 5120 * 4;
  float* WLt      = (float*)p;                  p += 5120 * 4;
  float* WL2t     = (float*)p;                  p += 5120 * 4;
  float* cL       = (float*)p;                  p += 32 * 4;
  float* o_un     = (float*)p;                  p += (size_t)B * 256 * 4;
  float* partial  = (float*)p;                  p += 256 * 20 * 4;
  float* Wpack    = (float*)p;                  p += 256 * 288 * 4;
  float* bpack    = (float*)p;                  p += 288 * 4;

  dim3 blk(256);
  // weight packing + kv + prep (all tiny)
  pack_kernel<<<dim3(288), blk, 0, stream>>>(W_off, b_off, W_attn, b_attn, Wpack, bpack);
  kv_kernel<<<dim3(3), blk, 0, stream>>>(unsup, conc, spat, Wkv_c, bkv_c,
                                         Wkv_s, bkv_s, kv_u, kv_n, kv_s);
  prep_kernel<<<dim3(20), blk, 0, stream>>>(Wq_s, bq_s, W_out, b_out, kv_s, WLt, WL2t, cL);
  // value = feats @ W_val + b_val (bf16 out)
  gemm_mfma<__hip_bfloat16><<<dim3(MV / 128, 2), blk, 0, stream>>>(
      feats, W_val, b_val, value, MV, 256, 256);
  // [off | logits] = query @ Wpack + bpack  (N=288)
  gemm_mfma<float><<<dim3(MQ / 128, 3), blk, 0, stream>>>(
      query, Wpack, bpack, offlog, MQ, 288, 256);
  // deformable sampling -> msda (bf16)
  msda_kernel2<<<dim3(MQ / 2), blk, 0, stream>>>(offlog, value, msda);
  // fused spatial branch (attn_s out + abar partials)
  spatial_kernel<<<dim3(MQ / 128), blk, 0, stream>>>(
      query, msda, WLt, WL2t, cL, out + 7040, partial);
  // cls branch
  cls_attn_kernel<<<dim3(B), dim3(64), 0, stream>>>(
      x_cls, Wq_c, bq_c, kv_u, kv_n, o_un, out + 6400, out + 6720);
  // final head
  final_out_kernel<<<dim3(B), blk, 0, stream>>>(
      o_un, partial, kv_s, Wp_c, bp_c, Wp_s, bp_s, out);
}

// Round 4
// 397.936 us; speedup vs baseline: 2.2777x; 1.0872x over previous
//
#include <hip/hip_runtime.h>
#include <hip/hip_bf16.h>

// ---------------------------------------------------------------------------
// B=32, LQ=1024, LIN=5376, D=256, NH=8, L=3, P=4, DH=32, NH_CA=2, M=10, NCLS=200
// Outputs (f32): out[6400) | attn_u[320) | attn_n[320) | attn_s[327680)
// Spatial branch is algebraically folded:
//   logits(b,q)[20] = query@WL + msda@WL2 + cL   (WL=scale*Wq_s@K^T, WL2=W_out@WL)
//   attn_s = mean_h softmax_h;  out_s.mean(q) = (sum_m abar[h,m] V[h,m])@Wp_s
// ---------------------------------------------------------------------------

typedef __attribute__((ext_vector_type(8))) short s16x8;
typedef __attribute__((ext_vector_type(4))) float f32x4;

__device__ __forceinline__ void store_val(float* p, float v) { *p = v; }
__device__ __forceinline__ void store_val(__hip_bfloat16* p, float v) { *p = __float2bfloat16(v); }

__device__ __forceinline__ unsigned short f2bf(float x) {
  unsigned int u = __builtin_bit_cast(unsigned int, x);
  u += 0x7FFFu + ((u >> 16) & 1u);  // RNE
  return (unsigned short)(u >> 16);
}
__device__ __forceinline__ float bf2f(unsigned short u) {
  return __builtin_bit_cast(float, (unsigned int)u << 16);
}
__device__ __forceinline__ float bflo(unsigned int u) {
  return __builtin_bit_cast(float, u << 16);
}
__device__ __forceinline__ float bfhi(unsigned int u) {
  return __builtin_bit_cast(float, u & 0xFFFF0000u);
}

// ---------------------------------------------------------------------------
// bf16-MFMA GEMM, coalesced A staging. C[M,N] = A[M,256] @ W[256,N] + bias.
// BM=128, BN=128, BK=64; 4 waves (2x2), wave tile 64x64. M%128==0, K==256.
// ---------------------------------------------------------------------------
template <typename OT>
__global__ __launch_bounds__(256, 2) void gemm_mfma(
    const float* __restrict__ A, const float* __restrict__ W,
    const float* __restrict__ bias, OT* __restrict__ C,
    int M, int N, int K /* == 256 */)
{
  __shared__ unsigned short sA[128 * 64];
  __shared__ unsigned short sB[128 * 64];
  char* sAb = (char*)sA;
  char* sBb = (char*)sB;

  const int tid = threadIdx.x;
  const int m0 = blockIdx.x * 128;
  const int n0 = blockIdx.y * 128;
  const int lane = tid & 63;
  const int w = tid >> 6;
  const int wr = (w >> 1) * 64, wc = (w & 1) * 64;
  const int l15 = lane & 15;
  const int lg = lane >> 4;

  const int a_row = tid >> 4;
  const int a_c4 = (tid & 15) * 4;
  const int a_swz = (a_row & 7) << 4;
  const int b_k8 = (tid >> 5) * 8;
  const int b_c4 = (tid & 31) * 4;
  const bool b_valid = (n0 + b_c4) < N;

  f32x4 acc[4][4] = {};
  f32x4 av[8], bv[8];

  const float* Abase = A + (size_t)(m0 + a_row) * K + a_c4;

#pragma unroll
  for (int it = 0; it < 8; ++it)
    av[it] = *reinterpret_cast<const f32x4*>(Abase + (size_t)it * 16 * K);
#pragma unroll
  for (int i = 0; i < 8; ++i)
    bv[i] = b_valid ? *reinterpret_cast<const f32x4*>(&W[(size_t)(b_k8 + i) * N + n0 + b_c4])
                    : f32x4{0.f, 0.f, 0.f, 0.f};

#pragma unroll
  for (int ks = 0; ks < 4; ++ks) {
    __syncthreads();
#pragma unroll
    for (int it = 0; it < 8; ++it) {
      uint2 p;
      p.x = (unsigned)f2bf(av[it][0]) | ((unsigned)f2bf(av[it][1]) << 16);
      p.y = (unsigned)f2bf(av[it][2]) | ((unsigned)f2bf(av[it][3]) << 16);
      const int off = (it * 16 + a_row) * 128 + ((a_c4 * 2) ^ a_swz);
      *reinterpret_cast<uint2*>(sAb + off) = p;
    }
#pragma unroll
    for (int j = 0; j < 4; ++j) {
      uint4 p;
      p.x = (unsigned)f2bf(bv[0][j]) | ((unsigned)f2bf(bv[1][j]) << 16);
      p.y = (unsigned)f2bf(bv[2][j]) | ((unsigned)f2bf(bv[3][j]) << 16);
      p.z = (unsigned)f2bf(bv[4][j]) | ((unsigned)f2bf(bv[5][j]) << 16);
      p.w = (unsigned)f2bf(bv[6][j]) | ((unsigned)f2bf(bv[7][j]) << 16);
      const int col = b_c4 + j;
      const int off = col * 128 + ((b_k8 * 2) ^ ((col & 7) << 4));
      *reinterpret_cast<uint4*>(sBb + off) = p;
    }
    __syncthreads();
    if (ks < 3) {
      const int k0 = (ks + 1) * 64;
#pragma unroll
      for (int it = 0; it < 8; ++it)
        av[it] = *reinterpret_cast<const f32x4*>(Abase + k0 + (size_t)it * 16 * K);
#pragma unroll
      for (int i = 0; i < 8; ++i)
        bv[i] = b_valid ? *reinterpret_cast<const f32x4*>(&W[(size_t)(k0 + b_k8 + i) * N + n0 + b_c4])
                        : f32x4{0.f, 0.f, 0.f, 0.f};
    }
#pragma unroll
    for (int kk = 0; kk < 2; ++kk) {
      const int kb = kk * 64 + lg * 16;
      s16x8 af[4], bf[4];
#pragma unroll
      for (int mf = 0; mf < 4; ++mf) {
        const int row = wr + mf * 16 + l15;
        af[mf] = *reinterpret_cast<const s16x8*>(sAb + row * 128 + (kb ^ ((row & 7) << 4)));
      }
#pragma unroll
      for (int nf = 0; nf < 4; ++nf) {
        const int col = wc + nf * 16 + l15;
        bf[nf] = *reinterpret_cast<const s16x8*>(sBb + col * 128 + (kb ^ ((col & 7) << 4)));
      }
#pragma unroll
      for (int mf = 0; mf < 4; ++mf)
#pragma unroll
        for (int nf = 0; nf < 4; ++nf)
          acc[mf][nf] = __builtin_amdgcn_mfma_f32_16x16x32_bf16(af[mf], bf[nf], acc[mf][nf], 0, 0, 0);
    }
  }

#pragma unroll
  for (int nf = 0; nf < 4; ++nf) {
    const int col = n0 + wc + nf * 16 + l15;
    if (col >= N) continue;
    const float bb = bias[col];
#pragma unroll
    for (int mf = 0; mf < 4; ++mf) {
#pragma unroll
      for (int j = 0; j < 4; ++j) {
        const int row = m0 + wr + mf * 16 + lg * 4 + j;
        store_val(&C[(size_t)row * N + col], acc[mf][nf][j] + bb);
      }
    }
  }
}

// pack [W_off | W_attn] -> Wpack[256][288], [b_off | b_attn] -> bpack[288]
__global__ __launch_bounds__(256) void pack_kernel(
    const float* __restrict__ W_off, const float* __restrict__ b_off,
    const float* __restrict__ W_attn, const float* __restrict__ b_attn,
    float* __restrict__ Wpack, float* __restrict__ bpack)
{
  const int idx = blockIdx.x * 256 + threadIdx.x;
  if (idx < 256 * 288) {
    const int k = idx / 288, j = idx % 288;
    Wpack[idx] = (j < 192) ? W_off[k * 192 + j] : W_attn[k * 96 + (j - 192)];
  }
  if (idx < 288) bpack[idx] = (idx < 192) ? b_off[idx] : b_attn[idx - 192];
}

// kv projections: dst[10][512] = src[10][256] @ W[256][512] + b
__global__ __launch_bounds__(256) void kv_kernel(
    const float* __restrict__ unsup, const float* __restrict__ conc,
    const float* __restrict__ spat, const float* __restrict__ Wkv_c,
    const float* __restrict__ bkv_c, const float* __restrict__ Wkv_s,
    const float* __restrict__ bkv_s, float* __restrict__ kv_u,
    float* __restrict__ kv_n, float* __restrict__ kv_s)
{
  const int j = blockIdx.x;
  const float* src = (j == 0) ? unsup : ((j == 1) ? conc : spat);
  const float* W   = (j < 2) ? Wkv_c : Wkv_s;
  const float* bb  = (j < 2) ? bkv_c : bkv_s;
  float* dst       = (j == 0) ? kv_u : ((j == 1) ? kv_n : kv_s);
  __shared__ float s[2560];
  for (int i = threadIdx.x; i < 2560; i += 256) s[i] = src[i];
  __syncthreads();
  for (int o = threadIdx.x; o < 5120; o += 256) {
    const int m = o >> 9, n = o & 511;
    float acc = bb[n];
    for (int k = 0; k < 256; ++k) acc += s[m * 256 + k] * W[(size_t)k * 512 + n];
    dst[o] = acc;
  }
}

// prep: per concept-column j=(h*10+m): WLt[j][256], WL2t[j][256], cL[j]
__global__ __launch_bounds__(256) void prep_kernel(
    const float* __restrict__ Wq_s, const float* __restrict__ bq_s,
    const float* __restrict__ W_out, const float* __restrict__ b_out,
    const float* __restrict__ kv_s, float* __restrict__ WLt,
    float* __restrict__ WL2t, float* __restrict__ cL)
{
  const int j = blockIdx.x;
  const int h = j / 10, m = j % 10;
  const int tid = threadIdx.x;
  __shared__ float kk[128], wl[256], bred[256];
  if (tid < 128) kk[tid] = kv_s[m * 512 + h * 128 + tid];
  __syncthreads();
  float acc = 0.f;
  for (int e = 0; e < 128; ++e) acc += Wq_s[(size_t)tid * 256 + h * 128 + e] * kk[e];
  wl[tid] = acc;
  __syncthreads();
  float acc2 = 0.f;
  for (int t = 0; t < 256; ++t) acc2 += W_out[(size_t)tid * 256 + t] * wl[t];
  const float scale = 0.08838834764831845f;
  WLt[j * 256 + tid] = scale * acc;
  WL2t[j * 256 + tid] = scale * acc2;
  bred[tid] = b_out[tid] * wl[tid] + ((tid < 128) ? bq_s[h * 128 + tid] * kk[tid] : 0.f);
  __syncthreads();
  for (int s = 128; s > 0; s >>= 1) {
    if (tid < s) bred[tid] += bred[tid + s];
    __syncthreads();
  }
  if (tid == 0) cL[j] = scale * bred[0];
}

// ---------------------------------------------------------------------------
// MSDA sampling, 8 queries/block (32 threads/query), 16B gather loads.
// Phase 1 (tid<64): per-(q,h) softmax over 12 logits (direct global reads).
// Phase 2: 768 corner setups -> LDS int4 rows + float4 weights per (q,h,l,p).
// Phase 3: gather; lane = (qi=tid>>5, h=(tid>>2)&7, d4=tid&3) loads uint4
// (8 bf16) per corner; 48 loads/lane; bf16x8 packed store.
// ---------------------------------------------------------------------------
__global__ __launch_bounds__(256) void msda_kernel8(
    const float* __restrict__ offlog, const __hip_bfloat16* __restrict__ value,
    __hip_bfloat16* __restrict__ msda_out)
{
  const int bq0 = blockIdx.x * 8;
  const int b = bq0 >> 10;
  const int tid = threadIdx.x;
  __shared__ float aw[768];
  __shared__ int4 sRow[768];
  __shared__ float4 sW[768];

  if (tid < 64) {
    const int qi = tid >> 3, h = tid & 7;
    const float* lp = &offlog[(size_t)(bq0 + qi) * 288 + 192 + h * 12];
    float e[12];
    float mx = -1e30f;
#pragma unroll
    for (int i = 0; i < 12; ++i) { e[i] = lp[i]; mx = fmaxf(mx, e[i]); }
    float s = 0.f;
#pragma unroll
    for (int i = 0; i < 12; ++i) { e[i] = expf(e[i] - mx); s += e[i]; }
    const float inv = 1.f / s;
#pragma unroll
    for (int i = 0; i < 12; ++i) aw[qi * 96 + h * 12 + i] = e[i] * inv;
  }
  __syncthreads();

#pragma unroll
  for (int k = 0; k < 3; ++k) {
    const int j = k * 256 + tid;
    const int qi = j / 96, cc = j - qi * 96;
    const int q = (bq0 + qi) & 1023;
    const int h = cc / 12, r = cc - h * 12, l = r >> 2, p_ = r & 3;
    const int WHl[3] = {64, 32, 16};
    const int St[3] = {0, 4096, 5120};
    const float2 o2 = *reinterpret_cast<const float2*>(
        &offlog[(size_t)(bq0 + qi) * 288 + h * 24 + l * 8 + p_ * 2]);
    const float refx = ((q & 31) + 0.5f) * (1.0f / 32.0f);
    const float refy = ((q >> 5) + 0.5f) * (1.0f / 32.0f);
    const int WH = WHl[l];
    const float fw = (float)WH;
    const float lx = (refx + o2.x / fw) * fw - 0.5f;
    const float ly = (refy + o2.y / fw) * fw - 0.5f;
    const float fx = floorf(lx), fy = floorf(ly);
    const int x0 = (int)fx, y0 = (int)fy;
    const float dx = lx - fx, dy = ly - fy;
    const float a = aw[j];
    int rows[4];
    float ws[4];
#pragma unroll
    for (int c = 0; c < 4; ++c) {
      const int ix = x0 + (c & 1), iy = y0 + (c >> 1);
      const float wb = ((c & 1) ? dx : 1.f - dx) * ((c >> 1) ? dy : 1.f - dy);
      const bool valid = (ix >= 0) && (ix < WH) && (iy >= 0) && (iy < WH);
      const int cx = min(max(ix, 0), WH - 1);
      const int cy = min(max(iy, 0), WH - 1);
      rows[c] = St[l] + cy * WH + cx;
      ws[c] = valid ? wb * a : 0.f;
    }
    sRow[j] = int4{rows[0], rows[1], rows[2], rows[3]};
    sW[j] = float4{ws[0], ws[1], ws[2], ws[3]};
  }
  __syncthreads();

  const int qi = tid >> 5;
  const int h = (tid >> 2) & 7;
  const int d4 = tid & 3;
  const unsigned short* vb = (const unsigned short*)value
      + (size_t)b * (5376 * 256) + h * 32 + d4 * 8;
  const int cbase = qi * 96 + h * 12;
  float acc[8] = {};
#pragma unroll 4
  for (int s = 0; s < 12; ++s) {
    const int4 rows = sRow[cbase + s];
    const float4 wv = sW[cbase + s];
    const int ra[4] = {rows.x, rows.y, rows.z, rows.w};
    const float wa[4] = {wv.x, wv.y, wv.z, wv.w};
#pragma unroll
    for (int c = 0; c < 4; ++c) {
      const uint4 v = *reinterpret_cast<const uint4*>(vb + (size_t)ra[c] * 256);
      const float w = wa[c];
      acc[0] += w * bflo(v.x); acc[1] += w * bfhi(v.x);
      acc[2] += w * bflo(v.y); acc[3] += w * bfhi(v.y);
      acc[4] += w * bflo(v.z); acc[5] += w * bfhi(v.z);
      acc[6] += w * bflo(v.w); acc[7] += w * bfhi(v.w);
    }
  }
  uint4 o;
  o.x = (unsigned)f2bf(acc[0]) | ((unsigned)f2bf(acc[1]) << 16);
  o.y = (unsigned)f2bf(acc[2]) | ((unsigned)f2bf(acc[3]) << 16);
  o.z = (unsigned)f2bf(acc[4]) | ((unsigned)f2bf(acc[5]) << 16);
  o.w = (unsigned)f2bf(acc[6]) | ((unsigned)f2bf(acc[7]) << 16);
  *reinterpret_cast<uint4*>(
      (unsigned short*)msda_out + (size_t)(bq0 + qi) * 256 + h * 32 + d4 * 8) = o;
}

// fused spatial branch: logits = query@WLt + msda@WL2t + cL -> per-head
// softmax -> attn_s output + per-block abar partial sums.
__global__ __launch_bounds__(256) void spatial_kernel(
    const float* __restrict__ query, const __hip_bfloat16* __restrict__ msda,
    const float* __restrict__ WLt, const float* __restrict__ WL2t,
    const float* __restrict__ cL, float* __restrict__ attn_out,
    float* __restrict__ partial)
{
  __shared__ float wls[20][256];
  __shared__ float wl2s[20][256];
  __shared__ float red[128][20];
  const int tid = threadIdx.x;
  for (int i = tid; i < 5120; i += 256) {
    wls[i >> 8][i & 255] = WLt[i];
    wl2s[i >> 8][i & 255] = WL2t[i];
  }
  const int row_local = tid >> 1;
  const int half = tid & 1;
  const int row = blockIdx.x * 128 + row_local;
  float acc[20];
#pragma unroll
  for (int c = 0; c < 20; ++c) acc[c] = half ? 0.f : cL[c];
  __syncthreads();

  const float* qp = &query[(size_t)row * 256 + half * 128];
  const unsigned short* mp = (const unsigned short*)msda + (size_t)row * 256 + half * 128;
  const int kbase = half * 128;
  for (int k = 0; k < 128; k += 4) {
    const f32x4 q4 = *reinterpret_cast<const f32x4*>(qp + k);
    const uint2 mm = *reinterpret_cast<const uint2*>(mp + k);
    const float m0 = bf2f((unsigned short)mm.x);
    const float m1 = bf2f((unsigned short)(mm.x >> 16));
    const float m2 = bf2f((unsigned short)mm.y);
    const float m3 = bf2f((unsigned short)(mm.y >> 16));
#pragma unroll
    for (int c = 0; c < 20; ++c) {
      const f32x4 w4 = *reinterpret_cast<const f32x4*>(&wls[c][kbase + k]);
      const f32x4 v4 = *reinterpret_cast<const f32x4*>(&wl2s[c][kbase + k]);
      acc[c] += q4.x * w4.x + q4.y * w4.y + q4.z * w4.z + q4.w * w4.w
              + m0 * v4.x + m1 * v4.y + m2 * v4.z + m3 * v4.w;
    }
  }
  if (half == 1) {
#pragma unroll
    for (int c = 0; c < 20; ++c) red[row_local][c] = acc[c];
  }
  __syncthreads();
  if (half == 0) {
    float a[20];
#pragma unroll
    for (int c = 0; c < 20; ++c) a[c] = acc[c] + red[row_local][c];
#pragma unroll
    for (int h = 0; h < 2; ++h) {
      float mx = -1e30f;
#pragma unroll
      for (int m = 0; m < 10; ++m) mx = fmaxf(mx, a[h * 10 + m]);
      float s = 0.f;
#pragma unroll
      for (int m = 0; m < 10; ++m) { a[h * 10 + m] = expf(a[h * 10 + m] - mx); s += a[h * 10 + m]; }
      const float inv = 1.f / s;
#pragma unroll
      for (int m = 0; m < 10; ++m) a[h * 10 + m] *= inv;
    }
#pragma unroll
    for (int m = 0; m < 10; ++m)
      attn_out[(size_t)row * 10 + m] = 0.5f * (a[m] + a[10 + m]);
#pragma unroll
    for (int c = 0; c < 20; ++c) red[row_local][c] = a[c];
  }
  __syncthreads();
  if (tid < 20) {
    float s = 0.f;
    for (int r = 0; r < 128; ++r) s += red[r][tid];
    partial[blockIdx.x * 20 + tid] = s;
  }
}

// cls cross-attention (unsup + normal concepts). One 64-thread block per b.
__global__ __launch_bounds__(64) void cls_attn_kernel(
    const float* __restrict__ x_cls, const float* __restrict__ Wq_c,
    const float* __restrict__ bq_c, const float* __restrict__ kv_u,
    const float* __restrict__ kv_n, float* __restrict__ o_un,
    float* __restrict__ attn_u_out, float* __restrict__ attn_n_out)
{
  const int b = blockIdx.x;
  const int lane = threadIdx.x;
  __shared__ float xr[256];
  *reinterpret_cast<float4*>(&xr[lane * 4]) =
      *reinterpret_cast<const float4*>(&x_cls[(size_t)b * 256 + lane * 4]);
  __syncthreads();
  float4 q4 = *reinterpret_cast<const float4*>(&bq_c[lane * 4]);
  for (int k = 0; k < 256; ++k) {
    const float xk = xr[k];
    const float4 w = *reinterpret_cast<const float4*>(&Wq_c[(size_t)k * 256 + lane * 4]);
    q4.x += xk * w.x; q4.y += xk * w.y; q4.z += xk * w.z; q4.w += xk * w.w;
  }
  const float scale = 0.08838834764831845f;
  float4 osum = {0.f, 0.f, 0.f, 0.f};
  for (int cs = 0; cs < 2; ++cs) {
    const float* kv = cs ? kv_n : kv_u;
    float* aout = cs ? attn_n_out : attn_u_out;
    float attn[10];
    float mx = -1e30f;
#pragma unroll
    for (int m = 0; m < 10; ++m) {
      const float4 k4 = *reinterpret_cast<const float4*>(&kv[m * 512 + lane * 4]);
      float p = q4.x * k4.x + q4.y * k4.y + q4.z * k4.z + q4.w * k4.w;
      p += __shfl_xor(p, 1);  p += __shfl_xor(p, 2);  p += __shfl_xor(p, 4);
      p += __shfl_xor(p, 8);  p += __shfl_xor(p, 16);
      attn[m] = p * scale;
      mx = fmaxf(mx, attn[m]);
    }
    float s = 0.f;
#pragma unroll
    for (int m = 0; m < 10; ++m) { attn[m] = expf(attn[m] - mx); s += attn[m]; }
    const float inv = 1.f / s;
#pragma unroll
    for (int m = 0; m < 10; ++m) {
      attn[m] *= inv;
      const float am = 0.5f * (attn[m] + __shfl_xor(attn[m], 32));
      if (lane == m) aout[b * 10 + m] = am;
      const float4 v4 = *reinterpret_cast<const float4*>(&kv[m * 512 + 256 + lane * 4]);
      osum.x += attn[m] * v4.x; osum.y += attn[m] * v4.y;
      osum.z += attn[m] * v4.z; osum.w += attn[m] * v4.w;
    }
  }
  *reinterpret_cast<float4*>(&o_un[(size_t)b * 256 + lane * 4]) = osum;
}

// final head: abar from partials -> o_sbar via V_s -> out[b][200]
__global__ __launch_bounds__(256) void final_out_kernel(
    const float* __restrict__ o_un, const float* __restrict__ partial,
    const float* __restrict__ kv_s, const float* __restrict__ Wp_c,
    const float* __restrict__ bp_c, const float* __restrict__ Wp_s,
    const float* __restrict__ bp_s, float* __restrict__ out)
{
  const int b = blockIdx.x, c = threadIdx.x;
  __shared__ float ou[256], os[256], abar[20];
  if (c < 20) {
    float s = 0.f;
    for (int ch = 0; ch < 8; ++ch) s += partial[(b * 8 + ch) * 20 + c];
    abar[c] = s * (1.0f / 1024.0f);
  }
  ou[c] = o_un[(size_t)b * 256 + c];
  __syncthreads();
  const int h = c >> 7, d = c & 127;
  float s = 0.f;
#pragma unroll
  for (int m = 0; m < 10; ++m) s += abar[h * 10 + m] * kv_s[m * 512 + 256 + h * 128 + d];
  os[c] = s;
  __syncthreads();
  if (c < 200) {
    float acc = 2.f * bp_c[c] + bp_s[c];
    for (int dd = 0; dd < 256; ++dd)
      acc += ou[dd] * Wp_c[dd * 200 + c] + os[dd] * Wp_s[dd * 200 + c];
    out[b * 200 + c] = acc;
  }
}

extern "C" void kernel_launch(void* const* d_in, const int* in_sizes, int n_in,
                              void* d_out, int out_size, void* d_ws, size_t ws_size,
                              hipStream_t stream)
{
  const float* query  = (const float*)d_in[0];
  const float* feats  = (const float*)d_in[1];
  const float* x_cls  = (const float*)d_in[2];
  const float* W_off  = (const float*)d_in[3];
  const float* b_off  = (const float*)d_in[4];
  const float* W_attn = (const float*)d_in[5];
  const float* b_attn = (const float*)d_in[6];
  const float* W_val  = (const float*)d_in[7];
  const float* b_val  = (const float*)d_in[8];
  const float* W_out  = (const float*)d_in[9];
  const float* b_out  = (const float*)d_in[10];
  const float* unsup  = (const float*)d_in[11];
  const float* conc   = (const float*)d_in[12];
  const float* spat   = (const float*)d_in[13];
  const float* Wq_c   = (const float*)d_in[14];
  const float* bq_c   = (const float*)d_in[15];
  const float* Wkv_c  = (const float*)d_in[16];
  const float* bkv_c  = (const float*)d_in[17];
  const float* Wp_c   = (const float*)d_in[18];
  const float* bp_c   = (const float*)d_in[19];
  const float* Wq_s   = (const float*)d_in[20];
  const float* bq_s   = (const float*)d_in[21];
  const float* Wkv_s  = (const float*)d_in[22];
  const float* bkv_s  = (const float*)d_in[23];
  const float* Wp_s   = (const float*)d_in[24];
  const float* bp_s   = (const float*)d_in[25];
  float* out = (float*)d_out;

  const int B = 32, LQ = 1024, LIN = 5376;
  const int MQ = B * LQ;    // 32768
  const int MV = B * LIN;   // 172032

  char* p = (char*)d_ws;
  __hip_bfloat16* value = (__hip_bfloat16*)p;   p += (size_t)MV * 256 * 2;
  float* offlog   = (float*)p;                  p += (size_t)MQ * 288 * 4;
  __hip_bfloat16* msda = (__hip_bfloat16*)p;    p += (size_t)MQ * 256 * 2;
  float* kv_u     = (float*)p;                  p += 5120 * 4;
  float* kv_n     = (float*)p;                  p += 5120 * 4;
  float* kv_s     = (float*)p;                  p += 5120 * 4;
  float* WLt      = (float*)p;                  p += 5120 * 4;
  float* WL2t     = (float*)p;                  p += 5120 * 4;
  float* cL       = (float*)p;                  p += 32 * 4;
  float* o_un     = (float*)p;                  p += (size_t)B * 256 * 4;
  float* partial  = (float*)p;                  p += 256 * 20 * 4;
  float* Wpack    = (float*)p;                  p += 256 * 288 * 4;
  float* bpack    = (float*)p;                  p += 288 * 4;

  dim3 blk(256);
  pack_kernel<<<dim3(288), blk, 0, stream>>>(W_off, b_off, W_attn, b_attn, Wpack, bpack);
  kv_kernel<<<dim3(3), blk, 0, stream>>>(unsup, conc, spat, Wkv_c, bkv_c,
                                         Wkv_s, bkv_s, kv_u, kv_n, kv_s);
  prep_kernel<<<dim3(20), blk, 0, stream>>>(Wq_s, bq_s, W_out, b_out, kv_s, WLt, WL2t, cL);
  // value = feats @ W_val + b_val (bf16 out)
  gemm_mfma<__hip_bfloat16><<<dim3(MV / 128, 2), blk, 0, stream>>>(
      feats, W_val, b_val, value, MV, 256, 256);
  // [off | logits] = query @ Wpack + bpack  (N=288)
  gemm_mfma<float><<<dim3(MQ / 128, 3), blk, 0, stream>>>(
      query, Wpack, bpack, offlog, MQ, 288, 256);
  // deformable sampling -> msda (bf16), 8 queries/block
  msda_kernel8<<<dim3(MQ / 8), blk, 0, stream>>>(offlog, value, msda);
  // fused spatial branch (attn_s out + abar partials)
  spatial_kernel<<<dim3(MQ / 128), blk, 0, stream>>>(
      query, msda, WLt, WL2t, cL, out + 7040, partial);
  // cls branch
  cls_attn_kernel<<<dim3(B), dim3(64), 0, stream>>>(
      x_cls, Wq_c, bq_c, kv_u, kv_n, o_un, out + 6400, out + 6720);
  // final head
  final_out_kernel<<<dim3(B), blk, 0, stream>>>(
      o_un, partial, kv_s, Wp_c, bp_c, Wp_s, bp_s, out);
}